// Round 1
// baseline (1950.600 us; speedup 1.0000x reference)
//
#include <hip/hip_runtime.h>
#include <hip/hip_bf16.h>
#include <math.h>

#define B_ 2
#define N_ 2048
#define D_ 512
#define E_ 1024
#define S_ 16
#define KC_ 4
#define R_ 32
#define C_ 512

// ---------------- LayerNorm stats (mu, rsqrt(var+eps)) per token ----------------
__global__ __launch_bounds__(256) void ln_stats_kernel(const float* __restrict__ x,
                                                       float2* __restrict__ stats) {
    int t = blockIdx.x;          // token 0..B*N-1
    int tid = threadIdx.x;       // 256 threads, 2 elems each (D=512)
    float2 v = *(const float2*)(x + (size_t)t * D_ + tid * 2);
    float s = v.x + v.y;
    float s2 = fmaf(v.x, v.x, v.y * v.y);
#pragma unroll
    for (int o = 32; o >= 1; o >>= 1) {
        s += __shfl_down(s, o);
        s2 += __shfl_down(s2, o);
    }
    __shared__ float red[8];
    int wid = tid >> 6;
    if ((tid & 63) == 0) { red[wid] = s; red[4 + wid] = s2; }
    __syncthreads();
    if (tid == 0) {
        float sum = red[0] + red[1] + red[2] + red[3];
        float sum2 = red[4] + red[5] + red[6] + red[7];
        float mu = sum * (1.f / (float)D_);
        float var = sum2 * (1.f / (float)D_) - mu * mu;
        stats[t] = make_float2(mu, rsqrtf(var + 1e-5f));
    }
}

// ---------------- fp32 tiled GEMM, optional fused LN on A, optional FiLM epilogue ----------------
// C[M,N] = A[M,K] @ B[K,N]; row-major everywhere.
template <int BM, int BN, int BK, int TM, int TN, bool LN, bool FILM>
__global__ __launch_bounds__(256) void gemm_f32(
    const float* __restrict__ A, const float* __restrict__ B, float* __restrict__ C,
    int M, int N, int K,
    const float2* __restrict__ stats, const float* __restrict__ lng, const float* __restrict__ lnb,
    const float* __restrict__ gamma, const float* __restrict__ beta) {
    constexpr int THREADS = (BM / TM) * (BN / TN);
    __shared__ __align__(16) float As[BK * BM];   // transposed: As[k][m]
    __shared__ __align__(16) float Bs[BK * BN];   // Bs[k][n]
    int tid = threadIdx.x;
    int m0 = blockIdx.y * BM, n0 = blockIdx.x * BN;
    int tx = tid % (BN / TN), ty = tid / (BN / TN);

    float acc[TM][TN];
#pragma unroll
    for (int i = 0; i < TM; i++)
#pragma unroll
        for (int j = 0; j < TN; j++) acc[i][j] = 0.f;

    for (int k0 = 0; k0 < K; k0 += BK) {
        __syncthreads();
        // A tile: BM x BK, store transposed
        constexpr int A4 = BM * BK / 4;
#pragma unroll
        for (int i = tid; i < A4; i += THREADS) {
            int r = i / (BK / 4);
            int c4 = (i % (BK / 4)) * 4;
            float4 v = *(const float4*)(A + (size_t)(m0 + r) * K + k0 + c4);
            if (LN) {
                float2 st = stats[m0 + r];
                float4 gv = *(const float4*)(lng + k0 + c4);
                float4 bv = *(const float4*)(lnb + k0 + c4);
                v.x = (v.x - st.x) * st.y * gv.x + bv.x;
                v.y = (v.y - st.x) * st.y * gv.y + bv.y;
                v.z = (v.z - st.x) * st.y * gv.z + bv.z;
                v.w = (v.w - st.x) * st.y * gv.w + bv.w;
            }
            As[(c4 + 0) * BM + r] = v.x;
            As[(c4 + 1) * BM + r] = v.y;
            As[(c4 + 2) * BM + r] = v.z;
            As[(c4 + 3) * BM + r] = v.w;
        }
        // B tile: BK x BN, natural layout
        constexpr int B4 = BK * BN / 4;
#pragma unroll
        for (int i = tid; i < B4; i += THREADS) {
            int r = i / (BN / 4);
            int c4 = (i % (BN / 4)) * 4;
            *(float4*)(Bs + r * BN + c4) = *(const float4*)(B + (size_t)(k0 + r) * N + n0 + c4);
        }
        __syncthreads();
#pragma unroll
        for (int kk = 0; kk < BK; kk++) {
            float a[TM], b[TN];
#pragma unroll
            for (int i = 0; i < TM; i += 4) *(float4*)&a[i] = *(const float4*)(As + kk * BM + ty * TM + i);
#pragma unroll
            for (int j = 0; j < TN; j += 4) *(float4*)&b[j] = *(const float4*)(Bs + kk * BN + tx * TN + j);
#pragma unroll
            for (int i = 0; i < TM; i++)
#pragma unroll
                for (int j = 0; j < TN; j++) acc[i][j] = fmaf(a[i], b[j], acc[i][j]);
        }
    }
    // epilogue
#pragma unroll
    for (int i = 0; i < TM; i++) {
        int row = m0 + ty * TM + i;
#pragma unroll
        for (int j = 0; j < TN; j += 4) {
            int col = n0 + tx * TN + j;
            float4 v;
            v.x = acc[i][j]; v.y = acc[i][j + 1]; v.z = acc[i][j + 2]; v.w = acc[i][j + 3];
            if (FILM) {
                int bi = row >> 11;  // N_=2048 rows per batch
                const float* gp = gamma + bi * D_ + col;
                const float* bp = beta + bi * D_ + col;
                v.x = gp[0] * v.x + bp[0];
                v.y = gp[1] * v.y + bp[1];
                v.z = gp[2] * v.z + bp[2];
                v.w = gp[3] * v.w + bp[3];
            }
            *(float4*)(C + (size_t)row * N + col) = v;
        }
    }
}

// ---------------- depthwise causal conv (K=4) + SiLU ----------------
__global__ __launch_bounds__(256) void conv_silu_kernel(const float* __restrict__ xz,
                                                        const float* __restrict__ cw,
                                                        const float* __restrict__ cb,
                                                        float* __restrict__ uc) {
    int idx = blockIdx.x * 256 + threadIdx.x;  // over B*N*E
    int e = idx & (E_ - 1);
    int bn = idx >> 10;           // row index (E=1024)
    int n = bn & (N_ - 1);
    const float4 w = *(const float4*)(cw + e * 4);   // conv_w[e][0..3]
    const float* up = xz + (size_t)bn * (2 * E_) + e;  // u[b,n,e]
    float acc = cb[e];
    acc = fmaf(up[0], w.w, acc);                                  // k=3 -> u[n]
    if (n >= 1) acc = fmaf(up[-(ptrdiff_t)(2 * E_)], w.z, acc);   // u[n-1]
    if (n >= 2) acc = fmaf(up[-(ptrdiff_t)(4 * E_)], w.y, acc);   // u[n-2]
    if (n >= 3) acc = fmaf(up[-(ptrdiff_t)(6 * E_)], w.x, acc);   // u[n-3]
    float sig = 1.f / (1.f + __expf(-acc));
    uc[idx] = acc * sig;
}

// ---------------- x_proj: x_dbl = uc @ W_x  [4096,1024]@[1024,64] ----------------
__global__ __launch_bounds__(256) void xproj_kernel(const float* __restrict__ uc,
                                                    const float* __restrict__ Wx,
                                                    float* __restrict__ xdbl) {
    int row0 = blockIdx.x * 8;
    int tid = threadIdx.x;
    __shared__ __align__(16) float lds[8 * E_];  // 32KB
#pragma unroll
    for (int i = tid; i < 8 * E_ / 4; i += 256) {
        int r = i >> 8;            // 256 float4 per row
        int c4 = (i & 255) * 4;
        *(float4*)&lds[r * E_ + c4] = *(const float4*)(uc + (size_t)(row0 + r) * E_ + c4);
    }
    __syncthreads();
    int c = tid & 63;
    int rr = tid >> 6;  // 0..3 -> rows rr and rr+4
    float a0 = 0.f, a1 = 0.f;
#pragma unroll 4
    for (int k = 0; k < E_; k++) {
        float w = Wx[k * 64 + c];
        a0 = fmaf(lds[rr * E_ + k], w, a0);
        a1 = fmaf(lds[(rr + 4) * E_ + k], w, a1);
    }
    xdbl[(size_t)(row0 + rr) * 64 + c] = a0;
    xdbl[(size_t)(row0 + rr + 4) * 64 + c] = a1;
}

// ---------------- delta = softplus(dt @ W_dt + b_dt)  K=32 ----------------
__global__ __launch_bounds__(256) void dt_kernel(const float* __restrict__ xdbl,
                                                 const float* __restrict__ Wdt,
                                                 const float* __restrict__ bdt,
                                                 float* __restrict__ delta) {
    int row0 = blockIdx.x * 8;
    int tid = threadIdx.x;
    __shared__ __align__(16) float dts[8 * 32];
    if (tid < 64) {
        int r = tid >> 3, c4 = (tid & 7) * 4;
        *(float4*)&dts[r * 32 + c4] = *(const float4*)(xdbl + (size_t)(row0 + r) * 64 + c4);
    }
    __syncthreads();
    float b4[4];
#pragma unroll
    for (int j = 0; j < 4; j++) b4[j] = bdt[tid + j * 256];
    float acc[8][4];
#pragma unroll
    for (int r = 0; r < 8; r++)
#pragma unroll
        for (int j = 0; j < 4; j++) acc[r][j] = 0.f;
#pragma unroll 4
    for (int k = 0; k < R_; k++) {
        float w[4];
#pragma unroll
        for (int j = 0; j < 4; j++) w[j] = Wdt[k * E_ + tid + j * 256];
#pragma unroll
        for (int r = 0; r < 8; r++) {
            float dv = dts[r * 32 + k];
#pragma unroll
            for (int j = 0; j < 4; j++) acc[r][j] = fmaf(dv, w[j], acc[r][j]);
        }
    }
#pragma unroll
    for (int r = 0; r < 8; r++)
#pragma unroll
        for (int j = 0; j < 4; j++) {
            float xv = acc[r][j] + b4[j];
            float sp = (xv > 20.f) ? xv : log1pf(__expf(xv));
            delta[(size_t)(row0 + r) * E_ + tid + j * 256] = sp;
        }
}

// ---------------- FiLM gamma/beta: cond @ film_w + film_b ----------------
__global__ __launch_bounds__(256) void film_kernel(const float* __restrict__ cond,
                                                   const float* __restrict__ gw,
                                                   const float* __restrict__ gb,
                                                   const float* __restrict__ bw,
                                                   const float* __restrict__ bb,
                                                   float* __restrict__ gamma,
                                                   float* __restrict__ beta) {
    int b = blockIdx.x;
    int tid = threadIdx.x;
    __shared__ __align__(16) float cs[C_];
    if (tid < 128) *(float4*)&cs[tid * 4] = *(const float4*)(cond + (size_t)b * C_ + tid * 4);
    __syncthreads();
#pragma unroll
    for (int dd = 0; dd < D_; dd += 256) {
        int d = dd + tid;
        float g = gb[d], bt = bb[d];
#pragma unroll 4
        for (int k = 0; k < C_; k++) {
            float cv = cs[k];
            g = fmaf(cv, gw[k * D_ + d], g);
            bt = fmaf(cv, bw[k * D_ + d], bt);
        }
        gamma[(size_t)b * D_ + d] = g;
        beta[(size_t)b * D_ + d] = bt;
    }
}

// ---------------- selective scan: thread per (b,e,s), shfl reduce over s ----------------
__global__ __launch_bounds__(256) void scan_kernel(const float* __restrict__ delta,
                                                   const float* __restrict__ uc,
                                                   const float* __restrict__ xdbl,
                                                   const float* __restrict__ xz,
                                                   const float* __restrict__ A_log,
                                                   const float* __restrict__ D_skip,
                                                   float* __restrict__ y) {
    int b = blockIdx.x >> 6;              // 64 blocks per batch
    int e0 = (blockIdx.x & 63) << 4;      // 16 e per block
    int tid = threadIdx.x;
    int s = tid & 15;
    int e = e0 + (tid >> 4);
    float Aes = -__expf(A_log[e * S_ + s]);
    float dsk = D_skip[e];
    float h = 0.f;
    const float* dp = delta + (size_t)b * N_ * E_ + e;
    const float* up = uc + (size_t)b * N_ * E_ + e;
    const float* bc = xdbl + (size_t)b * N_ * 64;
    const float* zp = xz + (size_t)b * N_ * (2 * E_) + E_ + e;
    float* yp = y + (size_t)b * N_ * E_ + e;
    for (int n = 0; n < N_; n++) {
        float dv = dp[(size_t)n * E_];
        float uv = up[(size_t)n * E_];
        float Bv = bc[n * 64 + R_ + s];
        float Cv = bc[n * 64 + R_ + S_ + s];
        float dA = __expf(dv * Aes);
        h = fmaf(dA, h, dv * uv * Bv);
        float p = h * Cv;
        p += __shfl_xor(p, 8, 16);
        p += __shfl_xor(p, 4, 16);
        p += __shfl_xor(p, 2, 16);
        p += __shfl_xor(p, 1, 16);
        if (s == 0) {
            float zv = zp[(size_t)n * 2 * E_];
            float yy = p + dsk * uv;
            yy = yy * (zv / (1.f + __expf(-zv)));
            yp[(size_t)n * E_] = yy;   // y aliases delta[b,n,e]: read-before-write in-wave
        }
    }
}

extern "C" void kernel_launch(void* const* d_in, const int* in_sizes, int n_in,
                              void* d_out, int out_size, void* d_ws, size_t ws_size,
                              hipStream_t stream) {
    const float* x       = (const float*)d_in[0];
    const float* cond    = (const float*)d_in[1];
    const float* ln_g    = (const float*)d_in[2];
    const float* ln_b    = (const float*)d_in[3];
    const float* W_in    = (const float*)d_in[4];
    const float* conv_w  = (const float*)d_in[5];
    const float* conv_b  = (const float*)d_in[6];
    const float* W_x     = (const float*)d_in[7];
    const float* W_dt    = (const float*)d_in[8];
    const float* b_dt    = (const float*)d_in[9];
    const float* A_log   = (const float*)d_in[10];
    const float* D_skip  = (const float*)d_in[11];
    const float* W_out   = (const float*)d_in[12];
    const float* film_gw = (const float*)d_in[13];
    const float* film_gb = (const float*)d_in[14];
    const float* film_bw = (const float*)d_in[15];
    const float* film_bb = (const float*)d_in[16];
    float* out = (float*)d_out;

    float* ws = (float*)d_ws;
    float* xz    = ws;                     // B*N*2E  = 8,388,608 f
    float* ucb   = xz + 8388608;           // B*N*E   = 4,194,304 f
    float* xdbl  = ucb + 4194304;          // B*N*64  =   262,144 f
    float* delta = xdbl + 262144;          // B*N*E   = 4,194,304 f
    float* gamma = delta + 4194304;        // B*D     =     1,024 f
    float* beta  = gamma + 1024;           // B*D     =     1,024 f
    float2* stats = (float2*)(beta + 1024);// B*N     =     4,096 f2
    float* y = delta;                      // alias (scan reads delta[b,n,e] before writing y[b,n,e])

    ln_stats_kernel<<<B_ * N_, 256, 0, stream>>>(x, stats);

    // xz = LN(x) @ W_in   [4096,512]@[512,2048]
    gemm_f32<128, 128, 16, 8, 8, true, false>
        <<<dim3(2048 / 128, 4096 / 128), 256, 0, stream>>>(
            x, W_in, xz, B_ * N_, 2 * E_, D_, stats, ln_g, ln_b, nullptr, nullptr);

    conv_silu_kernel<<<(B_ * N_ * E_) / 256, 256, 0, stream>>>(xz, conv_w, conv_b, ucb);

    xproj_kernel<<<(B_ * N_) / 8, 256, 0, stream>>>(ucb, W_x, xdbl);

    dt_kernel<<<(B_ * N_) / 8, 256, 0, stream>>>(xdbl, W_dt, b_dt, delta);

    film_kernel<<<B_, 256, 0, stream>>>(cond, film_gw, film_gb, film_bw, film_bb, gamma, beta);

    scan_kernel<<<B_ * (E_ / 16), 256, 0, stream>>>(delta, ucb, xdbl, xz, A_log, D_skip, y);

    // out = FiLM(y @ W_out)   [4096,1024]@[1024,512]
    gemm_f32<128, 64, 16, 8, 4, false, true>
        <<<dim3(512 / 64, 4096 / 128), 256, 0, stream>>>(
            y, W_out, out, B_ * N_, D_, E_, nullptr, nullptr, nullptr, gamma, beta);
}

// Round 2
// 567.069 us; speedup vs baseline: 3.4398x; 3.4398x over previous
//
#include <hip/hip_runtime.h>
#include <hip/hip_bf16.h>
#include <math.h>

#define B_ 2
#define N_ 2048
#define D_ 512
#define E_ 1024
#define S_ 16
#define KC_ 4
#define R_ 32
#define C_ 512
#define CH_ 128
#define NC_ (N_ / CH_)   // 16 chunks

// ---------------- LayerNorm stats (mu, rsqrt(var+eps)) per token ----------------
__global__ __launch_bounds__(256) void ln_stats_kernel(const float* __restrict__ x,
                                                       float2* __restrict__ stats) {
    int t = blockIdx.x;          // token 0..B*N-1
    int tid = threadIdx.x;       // 256 threads, 2 elems each (D=512)
    float2 v = *(const float2*)(x + (size_t)t * D_ + tid * 2);
    float s = v.x + v.y;
    float s2 = fmaf(v.x, v.x, v.y * v.y);
#pragma unroll
    for (int o = 32; o >= 1; o >>= 1) {
        s += __shfl_down(s, o);
        s2 += __shfl_down(s2, o);
    }
    __shared__ float red[8];
    int wid = tid >> 6;
    if ((tid & 63) == 0) { red[wid] = s; red[4 + wid] = s2; }
    __syncthreads();
    if (tid == 0) {
        float sum = red[0] + red[1] + red[2] + red[3];
        float sum2 = red[4] + red[5] + red[6] + red[7];
        float mu = sum * (1.f / (float)D_);
        float var = sum2 * (1.f / (float)D_) - mu * mu;
        stats[t] = make_float2(mu, rsqrtf(var + 1e-5f));
    }
}

// ---------------- fp32 tiled GEMM, optional fused LN on A, optional FiLM epilogue ----------------
template <int BM, int BN, int BK, int TM, int TN, bool LN, bool FILM>
__global__ __launch_bounds__(256) void gemm_f32(
    const float* __restrict__ A, const float* __restrict__ B, float* __restrict__ C,
    int M, int N, int K,
    const float2* __restrict__ stats, const float* __restrict__ lng, const float* __restrict__ lnb,
    const float* __restrict__ gamma, const float* __restrict__ beta) {
    constexpr int THREADS = (BM / TM) * (BN / TN);
    __shared__ __align__(16) float As[BK * BM];   // transposed: As[k][m]
    __shared__ __align__(16) float Bs[BK * BN];   // Bs[k][n]
    int tid = threadIdx.x;
    int m0 = blockIdx.y * BM, n0 = blockIdx.x * BN;
    int tx = tid % (BN / TN), ty = tid / (BN / TN);

    float acc[TM][TN];
#pragma unroll
    for (int i = 0; i < TM; i++)
#pragma unroll
        for (int j = 0; j < TN; j++) acc[i][j] = 0.f;

    for (int k0 = 0; k0 < K; k0 += BK) {
        __syncthreads();
        constexpr int A4 = BM * BK / 4;
#pragma unroll
        for (int i = tid; i < A4; i += THREADS) {
            int r = i / (BK / 4);
            int c4 = (i % (BK / 4)) * 4;
            float4 v = *(const float4*)(A + (size_t)(m0 + r) * K + k0 + c4);
            if (LN) {
                float2 st = stats[m0 + r];
                float4 gv = *(const float4*)(lng + k0 + c4);
                float4 bv = *(const float4*)(lnb + k0 + c4);
                v.x = (v.x - st.x) * st.y * gv.x + bv.x;
                v.y = (v.y - st.x) * st.y * gv.y + bv.y;
                v.z = (v.z - st.x) * st.y * gv.z + bv.z;
                v.w = (v.w - st.x) * st.y * gv.w + bv.w;
            }
            As[(c4 + 0) * BM + r] = v.x;
            As[(c4 + 1) * BM + r] = v.y;
            As[(c4 + 2) * BM + r] = v.z;
            As[(c4 + 3) * BM + r] = v.w;
        }
        constexpr int B4 = BK * BN / 4;
#pragma unroll
        for (int i = tid; i < B4; i += THREADS) {
            int r = i / (BN / 4);
            int c4 = (i % (BN / 4)) * 4;
            *(float4*)(Bs + r * BN + c4) = *(const float4*)(B + (size_t)(k0 + r) * N + n0 + c4);
        }
        __syncthreads();
#pragma unroll
        for (int kk = 0; kk < BK; kk++) {
            float a[TM], b[TN];
#pragma unroll
            for (int i = 0; i < TM; i += 4) *(float4*)&a[i] = *(const float4*)(As + kk * BM + ty * TM + i);
#pragma unroll
            for (int j = 0; j < TN; j += 4) *(float4*)&b[j] = *(const float4*)(Bs + kk * BN + tx * TN + j);
#pragma unroll
            for (int i = 0; i < TM; i++)
#pragma unroll
                for (int j = 0; j < TN; j++) acc[i][j] = fmaf(a[i], b[j], acc[i][j]);
        }
    }
#pragma unroll
    for (int i = 0; i < TM; i++) {
        int row = m0 + ty * TM + i;
#pragma unroll
        for (int j = 0; j < TN; j += 4) {
            int col = n0 + tx * TN + j;
            float4 v;
            v.x = acc[i][j]; v.y = acc[i][j + 1]; v.z = acc[i][j + 2]; v.w = acc[i][j + 3];
            if (FILM) {
                int bi = row >> 11;  // N_=2048 rows per batch
                const float* gp = gamma + bi * D_ + col;
                const float* bp = beta + bi * D_ + col;
                v.x = gp[0] * v.x + bp[0];
                v.y = gp[1] * v.y + bp[1];
                v.z = gp[2] * v.z + bp[2];
                v.w = gp[3] * v.w + bp[3];
            }
            *(float4*)(C + (size_t)row * N + col) = v;
        }
    }
}

// ---------------- depthwise causal conv (K=4) + SiLU ----------------
__global__ __launch_bounds__(256) void conv_silu_kernel(const float* __restrict__ xz,
                                                        const float* __restrict__ cw,
                                                        const float* __restrict__ cb,
                                                        float* __restrict__ uc) {
    int idx = blockIdx.x * 256 + threadIdx.x;  // over B*N*E
    int e = idx & (E_ - 1);
    int bn = idx >> 10;           // row index (E=1024)
    int n = bn & (N_ - 1);
    const float4 w = *(const float4*)(cw + e * 4);
    const float* up = xz + (size_t)bn * (2 * E_) + e;
    float acc = cb[e];
    acc = fmaf(up[0], w.w, acc);
    if (n >= 1) acc = fmaf(up[-(ptrdiff_t)(2 * E_)], w.z, acc);
    if (n >= 2) acc = fmaf(up[-(ptrdiff_t)(4 * E_)], w.y, acc);
    if (n >= 3) acc = fmaf(up[-(ptrdiff_t)(6 * E_)], w.x, acc);
    float sig = 1.f / (1.f + __expf(-acc));
    uc[idx] = acc * sig;
}

// ---------------- x_proj: x_dbl = uc @ W_x  [4096,1024]@[1024,64] ----------------
__global__ __launch_bounds__(256) void xproj_kernel(const float* __restrict__ uc,
                                                    const float* __restrict__ Wx,
                                                    float* __restrict__ xdbl) {
    int row0 = blockIdx.x * 8;
    int tid = threadIdx.x;
    __shared__ __align__(16) float lds[8 * E_];
#pragma unroll
    for (int i = tid; i < 8 * E_ / 4; i += 256) {
        int r = i >> 8;
        int c4 = (i & 255) * 4;
        *(float4*)&lds[r * E_ + c4] = *(const float4*)(uc + (size_t)(row0 + r) * E_ + c4);
    }
    __syncthreads();
    int c = tid & 63;
    int rr = tid >> 6;
    float a0 = 0.f, a1 = 0.f;
#pragma unroll 4
    for (int k = 0; k < E_; k++) {
        float w = Wx[k * 64 + c];
        a0 = fmaf(lds[rr * E_ + k], w, a0);
        a1 = fmaf(lds[(rr + 4) * E_ + k], w, a1);
    }
    xdbl[(size_t)(row0 + rr) * 64 + c] = a0;
    xdbl[(size_t)(row0 + rr + 4) * 64 + c] = a1;
}

// ---------------- delta = softplus(dt @ W_dt + b_dt)  K=32 ----------------
__global__ __launch_bounds__(256) void dt_kernel(const float* __restrict__ xdbl,
                                                 const float* __restrict__ Wdt,
                                                 const float* __restrict__ bdt,
                                                 float* __restrict__ delta) {
    int row0 = blockIdx.x * 8;
    int tid = threadIdx.x;
    __shared__ __align__(16) float dts[8 * 32];
    if (tid < 64) {
        int r = tid >> 3, c4 = (tid & 7) * 4;
        *(float4*)&dts[r * 32 + c4] = *(const float4*)(xdbl + (size_t)(row0 + r) * 64 + c4);
    }
    __syncthreads();
    float b4[4];
#pragma unroll
    for (int j = 0; j < 4; j++) b4[j] = bdt[tid + j * 256];
    float acc[8][4];
#pragma unroll
    for (int r = 0; r < 8; r++)
#pragma unroll
        for (int j = 0; j < 4; j++) acc[r][j] = 0.f;
#pragma unroll 4
    for (int k = 0; k < R_; k++) {
        float w[4];
#pragma unroll
        for (int j = 0; j < 4; j++) w[j] = Wdt[k * E_ + tid + j * 256];
#pragma unroll
        for (int r = 0; r < 8; r++) {
            float dv = dts[r * 32 + k];
#pragma unroll
            for (int j = 0; j < 4; j++) acc[r][j] = fmaf(dv, w[j], acc[r][j]);
        }
    }
#pragma unroll
    for (int r = 0; r < 8; r++)
#pragma unroll
        for (int j = 0; j < 4; j++) {
            float xv = acc[r][j] + b4[j];
            float sp = (xv > 20.f) ? xv : log1pf(__expf(xv));
            delta[(size_t)(row0 + r) * E_ + tid + j * 256] = sp;
        }
}

// ---------------- FiLM gamma/beta: cond @ film_w + film_b ----------------
__global__ __launch_bounds__(256) void film_kernel(const float* __restrict__ cond,
                                                   const float* __restrict__ gw,
                                                   const float* __restrict__ gb,
                                                   const float* __restrict__ bw,
                                                   const float* __restrict__ bb,
                                                   float* __restrict__ gamma,
                                                   float* __restrict__ beta) {
    int b = blockIdx.x;
    int tid = threadIdx.x;
    __shared__ __align__(16) float cs[C_];
    if (tid < 128) *(float4*)&cs[tid * 4] = *(const float4*)(cond + (size_t)b * C_ + tid * 4);
    __syncthreads();
#pragma unroll
    for (int dd = 0; dd < D_; dd += 256) {
        int d = dd + tid;
        float g = gb[d], bt = bb[d];
#pragma unroll 4
        for (int k = 0; k < C_; k++) {
            float cv = cs[k];
            g = fmaf(cv, gw[k * D_ + d], g);
            bt = fmaf(cv, bw[k * D_ + d], bt);
        }
        gamma[(size_t)b * D_ + d] = g;
        beta[(size_t)b * D_ + d] = bt;
    }
}

// ---------------- chunked selective scan ----------------
// phase1: per-chunk local scan from h=0; store chunk-final h and prod(dA).
// Block = (b, chunk c, e-group of 16). Thread = (e_local, s).
__global__ __launch_bounds__(256) void scan_phase1(const float* __restrict__ delta,
                                                   const float* __restrict__ uc,
                                                   const float* __restrict__ xdbl,
                                                   const float* __restrict__ A_log,
                                                   float* __restrict__ hend,
                                                   float* __restrict__ Pprod) {
    int blk = blockIdx.x;                 // ((b*NC_+c)*64 + eg)
    int eg = blk & 63;
    int c = (blk >> 6) & (NC_ - 1);
    int b = blk >> 10;
    int tid = threadIdx.x;
    int s = tid & 15;
    int e = (eg << 4) + (tid >> 4);
    float Aes = -__expf(A_log[e * S_ + s]);
    float h = 0.f, pr = 1.f;
    int n0 = c * CH_;
    const float* dp = delta + (size_t)b * N_ * E_ + (size_t)n0 * E_ + e;
    const float* up = uc + (size_t)b * N_ * E_ + (size_t)n0 * E_ + e;
    const float* bc = xdbl + (size_t)b * N_ * 64 + (size_t)n0 * 64;
    for (int n = 0; n < CH_; n++) {
        float dv = dp[(size_t)n * E_];
        float uv = up[(size_t)n * E_];
        float Bv = bc[n * 64 + R_ + s];
        float dA = __expf(dv * Aes);
        h = fmaf(dA, h, dv * uv * Bv);
        pr *= dA;
    }
    size_t idx = (((size_t)(b * NC_ + c) * E_ + e) << 4) + s;
    hend[idx] = h;
    Pprod[idx] = pr;
}

// phase2: sequential combine over chunks (16 steps), h_in per chunk.
__global__ __launch_bounds__(256) void scan_combine(const float* __restrict__ hend,
                                                    const float* __restrict__ Pprod,
                                                    float* __restrict__ hin) {
    int idx = blockIdx.x * 256 + threadIdx.x;  // over B*E*S = 32768
    int b = idx >> 14;                         // E_*S_ = 16384
    int es = idx & 16383;
    float h = 0.f;
#pragma unroll
    for (int c = 0; c < NC_; c++) {
        size_t i = ((size_t)(b * NC_ + c) << 14) + es;
        hin[i] = h;
        h = fmaf(Pprod[i], h, hend[i]);
    }
}

// phase3: redo local scan seeded with hin; produce gated y.
__global__ __launch_bounds__(256) void scan_phase3(const float* __restrict__ delta,
                                                   const float* __restrict__ uc,
                                                   const float* __restrict__ xdbl,
                                                   const float* __restrict__ xz,
                                                   const float* __restrict__ A_log,
                                                   const float* __restrict__ D_skip,
                                                   const float* __restrict__ hin,
                                                   float* __restrict__ y) {
    int blk = blockIdx.x;
    int eg = blk & 63;
    int c = (blk >> 6) & (NC_ - 1);
    int b = blk >> 10;
    int tid = threadIdx.x;
    int s = tid & 15;
    int e = (eg << 4) + (tid >> 4);
    float Aes = -__expf(A_log[e * S_ + s]);
    float dsk = D_skip[e];
    float h = hin[(((size_t)(b * NC_ + c) * E_ + e) << 4) + s];
    int n0 = c * CH_;
    const float* dp = delta + (size_t)b * N_ * E_ + (size_t)n0 * E_ + e;
    const float* up = uc + (size_t)b * N_ * E_ + (size_t)n0 * E_ + e;
    const float* bc = xdbl + (size_t)b * N_ * 64 + (size_t)n0 * 64;
    const float* zp = xz + (size_t)b * N_ * (2 * E_) + (size_t)n0 * (2 * E_) + E_ + e;
    float* yp = y + (size_t)b * N_ * E_ + (size_t)n0 * E_ + e;
    for (int n = 0; n < CH_; n++) {
        float dv = dp[(size_t)n * E_];
        float uv = up[(size_t)n * E_];
        float Bv = bc[n * 64 + R_ + s];
        float Cv = bc[n * 64 + R_ + S_ + s];
        float dA = __expf(dv * Aes);
        h = fmaf(dA, h, dv * uv * Bv);
        float p = h * Cv;
        p += __shfl_xor(p, 8, 16);
        p += __shfl_xor(p, 4, 16);
        p += __shfl_xor(p, 2, 16);
        p += __shfl_xor(p, 1, 16);
        if (s == 0) {
            float zv = zp[(size_t)n * 2 * E_];
            float yy = p + dsk * uv;
            yy = yy * (zv / (1.f + __expf(-zv)));
            yp[(size_t)n * E_] = yy;   // y aliases delta: read-before-write within wave
        }
    }
}

extern "C" void kernel_launch(void* const* d_in, const int* in_sizes, int n_in,
                              void* d_out, int out_size, void* d_ws, size_t ws_size,
                              hipStream_t stream) {
    const float* x       = (const float*)d_in[0];
    const float* cond    = (const float*)d_in[1];
    const float* ln_g    = (const float*)d_in[2];
    const float* ln_b    = (const float*)d_in[3];
    const float* W_in    = (const float*)d_in[4];
    const float* conv_w  = (const float*)d_in[5];
    const float* conv_b  = (const float*)d_in[6];
    const float* W_x     = (const float*)d_in[7];
    const float* W_dt    = (const float*)d_in[8];
    const float* b_dt    = (const float*)d_in[9];
    const float* A_log   = (const float*)d_in[10];
    const float* D_skip  = (const float*)d_in[11];
    const float* W_out   = (const float*)d_in[12];
    const float* film_gw = (const float*)d_in[13];
    const float* film_gb = (const float*)d_in[14];
    const float* film_bw = (const float*)d_in[15];
    const float* film_bb = (const float*)d_in[16];
    float* out = (float*)d_out;

    float* ws = (float*)d_ws;
    float* xz    = ws;                     // B*N*2E  = 8,388,608 f
    float* ucb   = xz + 8388608;           // B*N*E   = 4,194,304 f
    float* xdbl  = ucb + 4194304;          // B*N*64  =   262,144 f
    float* delta = xdbl + 262144;          // B*N*E   = 4,194,304 f
    float* gamma = delta + 4194304;        // B*D     =     1,024 f
    float* beta  = gamma + 1024;           // B*D     =     1,024 f
    float2* stats = (float2*)(beta + 1024);// B*N     =     4,096 f2
    float* hend  = (float*)(stats + 4096); // B*NC*E*S =  524,288 f
    float* Pprod = hend + 524288;          //            524,288 f
    float* hin   = Pprod + 524288;         //            524,288 f
    float* y = delta;                      // alias

    ln_stats_kernel<<<B_ * N_, 256, 0, stream>>>(x, stats);

    gemm_f32<128, 128, 16, 8, 8, true, false>
        <<<dim3(2048 / 128, 4096 / 128), 256, 0, stream>>>(
            x, W_in, xz, B_ * N_, 2 * E_, D_, stats, ln_g, ln_b, nullptr, nullptr);

    conv_silu_kernel<<<(B_ * N_ * E_) / 256, 256, 0, stream>>>(xz, conv_w, conv_b, ucb);

    xproj_kernel<<<(B_ * N_) / 8, 256, 0, stream>>>(ucb, W_x, xdbl);

    dt_kernel<<<(B_ * N_) / 8, 256, 0, stream>>>(xdbl, W_dt, b_dt, delta);

    film_kernel<<<B_, 256, 0, stream>>>(cond, film_gw, film_gb, film_bw, film_bb, gamma, beta);

    scan_phase1<<<B_ * NC_ * 64, 256, 0, stream>>>(delta, ucb, xdbl, A_log, hend, Pprod);
    scan_combine<<<(B_ * E_ * S_) / 256, 256, 0, stream>>>(hend, Pprod, hin);
    scan_phase3<<<B_ * NC_ * 64, 256, 0, stream>>>(delta, ucb, xdbl, xz, A_log, D_skip, hin, y);

    gemm_f32<128, 64, 16, 8, 4, false, true>
        <<<dim3(512 / 64, 4096 / 128), 256, 0, stream>>>(
            y, W_out, out, B_ * N_, D_, E_, nullptr, nullptr, nullptr, gamma, beta);
}

// Round 3
// 404.278 us; speedup vs baseline: 4.8249x; 1.4027x over previous
//
#include <hip/hip_runtime.h>
#include <hip/hip_bf16.h>
#include <math.h>

#define B_ 2
#define N_ 2048
#define D_ 512
#define E_ 1024
#define S_ 16
#define KC_ 4
#define R_ 32
#define C_ 512
#define CH_ 128
#define NC_ (N_ / CH_)   // 16 chunks

using short8 = __attribute__((ext_vector_type(8))) short;
using f32x16 = __attribute__((ext_vector_type(16))) float;

__device__ __forceinline__ short f2bf(float f) {
    union { float f; unsigned u; } x; x.f = f;
    unsigned r = (x.u + 0x7fffu + ((x.u >> 16) & 1u)) >> 16;
    return (short)r;
}

// ---------------- LayerNorm stats (mu, rsqrt(var+eps)) per token ----------------
__global__ __launch_bounds__(256) void ln_stats_kernel(const float* __restrict__ x,
                                                       float2* __restrict__ stats) {
    int t = blockIdx.x;
    int tid = threadIdx.x;
    float2 v = *(const float2*)(x + (size_t)t * D_ + tid * 2);
    float s = v.x + v.y;
    float s2 = fmaf(v.x, v.x, v.y * v.y);
#pragma unroll
    for (int o = 32; o >= 1; o >>= 1) {
        s += __shfl_down(s, o);
        s2 += __shfl_down(s2, o);
    }
    __shared__ float red[8];
    int wid = tid >> 6;
    if ((tid & 63) == 0) { red[wid] = s; red[4 + wid] = s2; }
    __syncthreads();
    if (tid == 0) {
        float sum = red[0] + red[1] + red[2] + red[3];
        float sum2 = red[4] + red[5] + red[6] + red[7];
        float mu = sum * (1.f / (float)D_);
        float var = sum2 * (1.f / (float)D_) - mu * mu;
        stats[t] = make_float2(mu, rsqrtf(var + 1e-5f));
    }
}

// ---------------- apply LN, emit bf16 xn [B*N][D] ----------------
__global__ __launch_bounds__(256) void ln_apply_kernel(const float* __restrict__ x,
                                                       const float2* __restrict__ stats,
                                                       const float* __restrict__ g,
                                                       const float* __restrict__ b,
                                                       short* __restrict__ xnb) {
    int i = blockIdx.x * 256 + threadIdx.x;   // over B*N*D/4
    int t = i >> 7;                            // 128 float4 per row
    int c4 = (i & 127) * 4;
    float2 st = stats[t];
    float4 v = *(const float4*)(x + (size_t)t * D_ + c4);
    float4 gv = *(const float4*)(g + c4);
    float4 bv = *(const float4*)(b + c4);
    short4 o;
    o.x = f2bf((v.x - st.x) * st.y * gv.x + bv.x);
    o.y = f2bf((v.y - st.x) * st.y * gv.y + bv.y);
    o.z = f2bf((v.z - st.x) * st.y * gv.z + bv.z);
    o.w = f2bf((v.w - st.x) * st.y * gv.w + bv.w);
    *(short4*)(xnb + (size_t)t * D_ + c4) = o;
}

// ---------------- transpose fp32 [K][N] -> bf16 [N][K] ----------------
__global__ __launch_bounds__(256) void transpose_bf16_kernel(const float* __restrict__ W,
                                                             short* __restrict__ Wt,
                                                             int K, int N) {
    __shared__ float t[32][33];
    int n0 = blockIdx.x * 32, k0 = blockIdx.y * 32;
    int c = threadIdx.x & 31, r = threadIdx.x >> 5;
#pragma unroll
    for (int rr = r; rr < 32; rr += 8)
        t[rr][c] = W[(size_t)(k0 + rr) * N + n0 + c];
    __syncthreads();
#pragma unroll
    for (int rr = r; rr < 32; rr += 8)
        Wt[(size_t)(n0 + rr) * K + k0 + c] = f2bf(t[c][rr]);
}

// ---------------- bf16 MFMA GEMM: C[M][N] = A[M][K] * Bt[N][K]^T (+FiLM) ----------------
// A, Bt row-major along K (bf16). 256 threads = 4 waves in 2x2, wave tile WM x WN.
template <int BM, int BN, bool FILM>
__global__ __launch_bounds__(256) void gemm_bf16(
    const short* __restrict__ A, const short* __restrict__ Bt, float* __restrict__ C,
    int M, int N, int K,
    const float* __restrict__ gamma, const float* __restrict__ beta) {
    constexpr int BK = 64;
    constexpr int LDT = BK + 8;          // 72 shorts = 144B pitch (2-way max aliasing)
    constexpr int WM = BM / 2, WN = BN / 2;
    constexpr int MR = WM / 32, NR = WN / 32;
    __shared__ __align__(16) short As[BM * LDT];
    __shared__ __align__(16) short Bs[BN * LDT];
    int tid = threadIdx.x;
    int lane = tid & 63, w = tid >> 6;
    int wr = w >> 1, wc = w & 1;
    int m0 = blockIdx.y * BM, n0 = blockIdx.x * BN;

    f32x16 acc[MR][NR];
#pragma unroll
    for (int i = 0; i < MR; i++)
#pragma unroll
        for (int j = 0; j < NR; j++)
#pragma unroll
            for (int r = 0; r < 16; r++) acc[i][j][r] = 0.f;

    int l31 = lane & 31, hk = (lane >> 5) * 8;

    for (int k0 = 0; k0 < K; k0 += BK) {
        __syncthreads();
#pragma unroll
        for (int i = tid; i < BM * 8; i += 256) {
            int r = i >> 3, c = (i & 7) * 8;
            *(short8*)&As[r * LDT + c] = *(const short8*)&A[(size_t)(m0 + r) * K + k0 + c];
        }
#pragma unroll
        for (int i = tid; i < BN * 8; i += 256) {
            int r = i >> 3, c = (i & 7) * 8;
            *(short8*)&Bs[r * LDT + c] = *(const short8*)&Bt[(size_t)(n0 + r) * K + k0 + c];
        }
        __syncthreads();
#pragma unroll
        for (int kk = 0; kk < 4; kk++) {
            short8 a[MR], b[NR];
#pragma unroll
            for (int i = 0; i < MR; i++)
                a[i] = *(const short8*)&As[(wr * WM + i * 32 + l31) * LDT + kk * 16 + hk];
#pragma unroll
            for (int j = 0; j < NR; j++)
                b[j] = *(const short8*)&Bs[(wc * WN + j * 32 + l31) * LDT + kk * 16 + hk];
#pragma unroll
            for (int i = 0; i < MR; i++)
#pragma unroll
                for (int j = 0; j < NR; j++)
                    acc[i][j] = __builtin_amdgcn_mfma_f32_32x32x16_bf16(a[i], b[j], acc[i][j], 0, 0, 0);
        }
    }
    // epilogue: C/D layout col=lane&31, row=(r&3)+8*(r>>2)+4*(lane>>5)
    int rbase = 4 * (lane >> 5);
    int bi = m0 >> 11;   // batch index (BM=128 tiles never cross batch; N_=2048 rows/batch)
#pragma unroll
    for (int i = 0; i < MR; i++)
#pragma unroll
        for (int j = 0; j < NR; j++) {
            int col = n0 + wc * WN + j * 32 + l31;
            float gm = 1.f, bt = 0.f;
            if (FILM) {
                gm = gamma[bi * D_ + col];
                bt = beta[bi * D_ + col];
            }
#pragma unroll
            for (int r = 0; r < 16; r++) {
                int row = m0 + wr * WM + i * 32 + rbase + (r & 3) + 8 * (r >> 2);
                float v = acc[i][j][r];
                if (FILM) v = gm * v + bt;
                C[(size_t)row * N + col] = v;
            }
        }
}

// ---------------- depthwise causal conv (K=4) + SiLU ----------------
__global__ __launch_bounds__(256) void conv_silu_kernel(const float* __restrict__ xz,
                                                        const float* __restrict__ cw,
                                                        const float* __restrict__ cb,
                                                        float* __restrict__ uc) {
    int idx = blockIdx.x * 256 + threadIdx.x;  // over B*N*E
    int e = idx & (E_ - 1);
    int bn = idx >> 10;
    int n = bn & (N_ - 1);
    const float4 w = *(const float4*)(cw + e * 4);
    const float* up = xz + (size_t)bn * (2 * E_) + e;
    float acc = cb[e];
    acc = fmaf(up[0], w.w, acc);
    if (n >= 1) acc = fmaf(up[-(ptrdiff_t)(2 * E_)], w.z, acc);
    if (n >= 2) acc = fmaf(up[-(ptrdiff_t)(4 * E_)], w.y, acc);
    if (n >= 3) acc = fmaf(up[-(ptrdiff_t)(6 * E_)], w.x, acc);
    float sig = 1.f / (1.f + __expf(-acc));
    uc[idx] = acc * sig;
}

// ---------------- x_proj: x_dbl = uc @ W_x  [4096,1024]@[1024,64] ----------------
__global__ __launch_bounds__(256) void xproj_kernel(const float* __restrict__ uc,
                                                    const float* __restrict__ Wx,
                                                    float* __restrict__ xdbl) {
    int row0 = blockIdx.x * 8;
    int tid = threadIdx.x;
    __shared__ __align__(16) float lds[8 * E_];
#pragma unroll
    for (int i = tid; i < 8 * E_ / 4; i += 256) {
        int r = i >> 8;
        int c4 = (i & 255) * 4;
        *(float4*)&lds[r * E_ + c4] = *(const float4*)(uc + (size_t)(row0 + r) * E_ + c4);
    }
    __syncthreads();
    int c = tid & 63;
    int rr = tid >> 6;
    float a0 = 0.f, a1 = 0.f;
#pragma unroll 4
    for (int k = 0; k < E_; k++) {
        float w = Wx[k * 64 + c];
        a0 = fmaf(lds[rr * E_ + k], w, a0);
        a1 = fmaf(lds[(rr + 4) * E_ + k], w, a1);
    }
    xdbl[(size_t)(row0 + rr) * 64 + c] = a0;
    xdbl[(size_t)(row0 + rr + 4) * 64 + c] = a1;
}

// ---------------- delta = softplus(dt @ W_dt + b_dt)  K=32 ----------------
__global__ __launch_bounds__(256) void dt_kernel(const float* __restrict__ xdbl,
                                                 const float* __restrict__ Wdt,
                                                 const float* __restrict__ bdt,
                                                 float* __restrict__ delta) {
    int row0 = blockIdx.x * 8;
    int tid = threadIdx.x;
    __shared__ __align__(16) float dts[8 * 32];
    if (tid < 64) {
        int r = tid >> 3, c4 = (tid & 7) * 4;
        *(float4*)&dts[r * 32 + c4] = *(const float4*)(xdbl + (size_t)(row0 + r) * 64 + c4);
    }
    __syncthreads();
    float b4[4];
#pragma unroll
    for (int j = 0; j < 4; j++) b4[j] = bdt[tid + j * 256];
    float acc[8][4];
#pragma unroll
    for (int r = 0; r < 8; r++)
#pragma unroll
        for (int j = 0; j < 4; j++) acc[r][j] = 0.f;
#pragma unroll 4
    for (int k = 0; k < R_; k++) {
        float w[4];
#pragma unroll
        for (int j = 0; j < 4; j++) w[j] = Wdt[k * E_ + tid + j * 256];
#pragma unroll
        for (int r = 0; r < 8; r++) {
            float dv = dts[r * 32 + k];
#pragma unroll
            for (int j = 0; j < 4; j++) acc[r][j] = fmaf(dv, w[j], acc[r][j]);
        }
    }
#pragma unroll
    for (int r = 0; r < 8; r++)
#pragma unroll
        for (int j = 0; j < 4; j++) {
            float xv = acc[r][j] + b4[j];
            float sp = (xv > 20.f) ? xv : log1pf(__expf(xv));
            delta[(size_t)(row0 + r) * E_ + tid + j * 256] = sp;
        }
}

// ---------------- FiLM gamma/beta: cond @ film_w + film_b ----------------
__global__ __launch_bounds__(256) void film_kernel(const float* __restrict__ cond,
                                                   const float* __restrict__ gw,
                                                   const float* __restrict__ gb,
                                                   const float* __restrict__ bw,
                                                   const float* __restrict__ bb,
                                                   float* __restrict__ gamma,
                                                   float* __restrict__ beta) {
    int b = blockIdx.x;
    int tid = threadIdx.x;
    __shared__ __align__(16) float cs[C_];
    if (tid < 128) *(float4*)&cs[tid * 4] = *(const float4*)(cond + (size_t)b * C_ + tid * 4);
    __syncthreads();
#pragma unroll
    for (int dd = 0; dd < D_; dd += 256) {
        int d = dd + tid;
        float g = gb[d], bt = bb[d];
#pragma unroll 4
        for (int k = 0; k < C_; k++) {
            float cv = cs[k];
            g = fmaf(cv, gw[k * D_ + d], g);
            bt = fmaf(cv, bw[k * D_ + d], bt);
        }
        gamma[(size_t)b * D_ + d] = g;
        beta[(size_t)b * D_ + d] = bt;
    }
}

// ---------------- chunked selective scan ----------------
__global__ __launch_bounds__(256) void scan_phase1(const float* __restrict__ delta,
                                                   const float* __restrict__ uc,
                                                   const float* __restrict__ xdbl,
                                                   const float* __restrict__ A_log,
                                                   float* __restrict__ hend,
                                                   float* __restrict__ Pprod) {
    int blk = blockIdx.x;
    int eg = blk & 63;
    int c = (blk >> 6) & (NC_ - 1);
    int b = blk >> 10;
    int tid = threadIdx.x;
    int s = tid & 15;
    int e = (eg << 4) + (tid >> 4);
    float Aes = -__expf(A_log[e * S_ + s]);
    float h = 0.f, pr = 1.f;
    int n0 = c * CH_;
    const float* dp = delta + (size_t)b * N_ * E_ + (size_t)n0 * E_ + e;
    const float* up = uc + (size_t)b * N_ * E_ + (size_t)n0 * E_ + e;
    const float* bc = xdbl + (size_t)b * N_ * 64 + (size_t)n0 * 64;
    for (int n = 0; n < CH_; n++) {
        float dv = dp[(size_t)n * E_];
        float uv = up[(size_t)n * E_];
        float Bv = bc[n * 64 + R_ + s];
        float dA = __expf(dv * Aes);
        h = fmaf(dA, h, dv * uv * Bv);
        pr *= dA;
    }
    size_t idx = (((size_t)(b * NC_ + c) * E_ + e) << 4) + s;
    hend[idx] = h;
    Pprod[idx] = pr;
}

__global__ __launch_bounds__(256) void scan_combine(const float* __restrict__ hend,
                                                    const float* __restrict__ Pprod,
                                                    float* __restrict__ hin) {
    int idx = blockIdx.x * 256 + threadIdx.x;  // over B*E*S = 32768
    int b = idx >> 14;
    int es = idx & 16383;
    float h = 0.f;
#pragma unroll
    for (int c = 0; c < NC_; c++) {
        size_t i = ((size_t)(b * NC_ + c) << 14) + es;
        hin[i] = h;
        h = fmaf(Pprod[i], h, hend[i]);
    }
}

// phase3: local scan seeded with hin; produce gated y as bf16 (GEMM2 A-operand).
__global__ __launch_bounds__(256) void scan_phase3(const float* __restrict__ delta,
                                                   const float* __restrict__ uc,
                                                   const float* __restrict__ xdbl,
                                                   const float* __restrict__ xz,
                                                   const float* __restrict__ A_log,
                                                   const float* __restrict__ D_skip,
                                                   const float* __restrict__ hin,
                                                   short* __restrict__ yb) {
    int blk = blockIdx.x;
    int eg = blk & 63;
    int c = (blk >> 6) & (NC_ - 1);
    int b = blk >> 10;
    int tid = threadIdx.x;
    int s = tid & 15;
    int e = (eg << 4) + (tid >> 4);
    float Aes = -__expf(A_log[e * S_ + s]);
    float dsk = D_skip[e];
    float h = hin[(((size_t)(b * NC_ + c) * E_ + e) << 4) + s];
    int n0 = c * CH_;
    const float* dp = delta + (size_t)b * N_ * E_ + (size_t)n0 * E_ + e;
    const float* up = uc + (size_t)b * N_ * E_ + (size_t)n0 * E_ + e;
    const float* bc = xdbl + (size_t)b * N_ * 64 + (size_t)n0 * 64;
    const float* zp = xz + (size_t)b * N_ * (2 * E_) + (size_t)n0 * (2 * E_) + E_ + e;
    short* yp = yb + (size_t)b * N_ * E_ + (size_t)n0 * E_ + e;
    for (int n = 0; n < CH_; n++) {
        float dv = dp[(size_t)n * E_];
        float uv = up[(size_t)n * E_];
        float Bv = bc[n * 64 + R_ + s];
        float Cv = bc[n * 64 + R_ + S_ + s];
        float dA = __expf(dv * Aes);
        h = fmaf(dA, h, dv * uv * Bv);
        float p = h * Cv;
        p += __shfl_xor(p, 8, 16);
        p += __shfl_xor(p, 4, 16);
        p += __shfl_xor(p, 2, 16);
        p += __shfl_xor(p, 1, 16);
        if (s == 0) {
            float zv = zp[(size_t)n * 2 * E_];
            float yy = p + dsk * uv;
            yy = yy * (zv / (1.f + __expf(-zv)));
            yp[(size_t)n * E_] = f2bf(yy);
        }
    }
}

extern "C" void kernel_launch(void* const* d_in, const int* in_sizes, int n_in,
                              void* d_out, int out_size, void* d_ws, size_t ws_size,
                              hipStream_t stream) {
    const float* x       = (const float*)d_in[0];
    const float* cond    = (const float*)d_in[1];
    const float* ln_g    = (const float*)d_in[2];
    const float* ln_b    = (const float*)d_in[3];
    const float* W_in    = (const float*)d_in[4];
    const float* conv_w  = (const float*)d_in[5];
    const float* conv_b  = (const float*)d_in[6];
    const float* W_x     = (const float*)d_in[7];
    const float* W_dt    = (const float*)d_in[8];
    const float* b_dt    = (const float*)d_in[9];
    const float* A_log   = (const float*)d_in[10];
    const float* D_skip  = (const float*)d_in[11];
    const float* W_out   = (const float*)d_in[12];
    const float* film_gw = (const float*)d_in[13];
    const float* film_gb = (const float*)d_in[14];
    const float* film_bw = (const float*)d_in[15];
    const float* film_bb = (const float*)d_in[16];
    float* out = (float*)d_out;

    float* ws = (float*)d_ws;
    float* xz    = ws;                       // 8,388,608 f
    float* ucb   = xz + 8388608;             // 4,194,304 f
    float* xdbl  = ucb + 4194304;            //   262,144 f
    float* delta = xdbl + 262144;            // 4,194,304 f
    float* gamma = delta + 4194304;          //     1,024 f
    float* beta  = gamma + 1024;             //     1,024 f
    float2* stats = (float2*)(beta + 1024);  //     4,096 f2
    float* hend  = (float*)(stats + 4096);   //   524,288 f
    float* Pprod = hend + 524288;            //   524,288 f
    float* hin   = Pprod + 524288;           //   524,288 f
    short* xnb   = (short*)(hin + 524288);   // 2,097,152 sh (bf16 LN(x))
    short* Wint  = xnb + 2097152;            // 1,048,576 sh (W_in^T bf16 [2048][512])
    short* Woutt = Wint + 1048576;           //   524,288 sh (W_out^T bf16 [512][1024])
    short* yb    = Woutt + 524288;           // 4,194,304 sh (y bf16)

    ln_stats_kernel<<<B_ * N_, 256, 0, stream>>>(x, stats);
    ln_apply_kernel<<<(B_ * N_ * D_ / 4) / 256, 256, 0, stream>>>(x, stats, ln_g, ln_b, xnb);
    transpose_bf16_kernel<<<dim3(2 * E_ / 32, D_ / 32), 256, 0, stream>>>(W_in, Wint, D_, 2 * E_);
    transpose_bf16_kernel<<<dim3(D_ / 32, E_ / 32), 256, 0, stream>>>(W_out, Woutt, E_, D_);
    film_kernel<<<B_, 256, 0, stream>>>(cond, film_gw, film_gb, film_bw, film_bb, gamma, beta);

    // xz = xn @ W_in   [4096,512]x[512,2048] -> MFMA bf16
    gemm_bf16<128, 128, false>
        <<<dim3(2 * E_ / 128, B_ * N_ / 128), 256, 0, stream>>>(
            xnb, Wint, xz, B_ * N_, 2 * E_, D_, nullptr, nullptr);

    conv_silu_kernel<<<(B_ * N_ * E_) / 256, 256, 0, stream>>>(xz, conv_w, conv_b, ucb);

    xproj_kernel<<<(B_ * N_) / 8, 256, 0, stream>>>(ucb, W_x, xdbl);

    dt_kernel<<<(B_ * N_) / 8, 256, 0, stream>>>(xdbl, W_dt, b_dt, delta);

    scan_phase1<<<B_ * NC_ * 64, 256, 0, stream>>>(delta, ucb, xdbl, A_log, hend, Pprod);
    scan_combine<<<(B_ * E_ * S_) / 256, 256, 0, stream>>>(hend, Pprod, hin);
    scan_phase3<<<B_ * NC_ * 64, 256, 0, stream>>>(delta, ucb, xdbl, xz, A_log, D_skip, hin, yb);

    // out = FiLM(y @ W_out)   [4096,1024]x[1024,512] -> MFMA bf16, 256 blocks
    gemm_bf16<128, 64, true>
        <<<dim3(D_ / 64, B_ * N_ / 128), 256, 0, stream>>>(
            yb, Woutt, out, B_ * N_, D_, E_, gamma, beta);
}

// Round 4
// 260.090 us; speedup vs baseline: 7.4997x; 1.5544x over previous
//
#include <hip/hip_runtime.h>
#include <hip/hip_bf16.h>
#include <math.h>

#define B_ 2
#define N_ 2048
#define D_ 512
#define E_ 1024
#define S_ 16
#define KC_ 4
#define R_ 32
#define C_ 512
#define CH_ 32
#define NC_ (N_ / CH_)   // 64 chunks

using short8 = __attribute__((ext_vector_type(8))) short;
using f32x16 = __attribute__((ext_vector_type(16))) float;

__device__ __forceinline__ short f2bf(float f) {
    union { float f; unsigned u; } x; x.f = f;
    unsigned r = (x.u + 0x7fffu + ((x.u >> 16) & 1u)) >> 16;
    return (short)r;
}

// ---------------- LayerNorm stats (mu, rsqrt(var+eps)) per token ----------------
__global__ __launch_bounds__(256) void ln_stats_kernel(const float* __restrict__ x,
                                                       float2* __restrict__ stats) {
    int t = blockIdx.x;
    int tid = threadIdx.x;
    float2 v = *(const float2*)(x + (size_t)t * D_ + tid * 2);
    float s = v.x + v.y;
    float s2 = fmaf(v.x, v.x, v.y * v.y);
#pragma unroll
    for (int o = 32; o >= 1; o >>= 1) {
        s += __shfl_down(s, o);
        s2 += __shfl_down(s2, o);
    }
    __shared__ float red[8];
    int wid = tid >> 6;
    if ((tid & 63) == 0) { red[wid] = s; red[4 + wid] = s2; }
    __syncthreads();
    if (tid == 0) {
        float sum = red[0] + red[1] + red[2] + red[3];
        float sum2 = red[4] + red[5] + red[6] + red[7];
        float mu = sum * (1.f / (float)D_);
        float var = sum2 * (1.f / (float)D_) - mu * mu;
        stats[t] = make_float2(mu, rsqrtf(var + 1e-5f));
    }
}

// ---------------- transpose fp32 [K][N] -> bf16 [N][K] ----------------
__global__ __launch_bounds__(256) void transpose_bf16_kernel(const float* __restrict__ W,
                                                             short* __restrict__ Wt,
                                                             int K, int N) {
    __shared__ float t[32][33];
    int n0 = blockIdx.x * 32, k0 = blockIdx.y * 32;
    int c = threadIdx.x & 31, r = threadIdx.x >> 5;
#pragma unroll
    for (int rr = r; rr < 32; rr += 8)
        t[rr][c] = W[(size_t)(k0 + rr) * N + n0 + c];
    __syncthreads();
#pragma unroll
    for (int rr = r; rr < 32; rr += 8)
        Wt[(size_t)(n0 + rr) * K + k0 + c] = f2bf(t[c][rr]);
}

// ---------------- bf16 MFMA GEMM: C[M][N] = A[M][K] * Bt[N][K]^T ----------------
// LNA: A is fp32, LayerNorm applied during staging. FILM: fused gamma/beta epilogue.
template <int BM, int BN, bool FILM, bool LNA>
__global__ __launch_bounds__(256) void gemm_bf16(
    const void* __restrict__ Av, const short* __restrict__ Bt, float* __restrict__ C,
    int M, int N, int K,
    const float2* __restrict__ stats, const float* __restrict__ lng, const float* __restrict__ lnb,
    const float* __restrict__ gamma, const float* __restrict__ beta) {
    constexpr int BK = 64;
    constexpr int LDT = BK + 8;          // 72 shorts = 144B pitch
    constexpr int WM = BM / 2, WN = BN / 2;
    constexpr int MR = WM / 32, NR = WN / 32;
    __shared__ __align__(16) short As[BM * LDT];
    __shared__ __align__(16) short Bs[BN * LDT];
    int tid = threadIdx.x;
    int lane = tid & 63, w = tid >> 6;
    int wr = w >> 1, wc = w & 1;
    int m0 = blockIdx.y * BM, n0 = blockIdx.x * BN;

    f32x16 acc[MR][NR];
#pragma unroll
    for (int i = 0; i < MR; i++)
#pragma unroll
        for (int j = 0; j < NR; j++)
#pragma unroll
            for (int r = 0; r < 16; r++) acc[i][j][r] = 0.f;

    int l31 = lane & 31, hk = (lane >> 5) * 8;

    for (int k0 = 0; k0 < K; k0 += BK) {
        __syncthreads();
        if constexpr (LNA) {
            const float* Af = (const float*)Av;
#pragma unroll
            for (int i = tid; i < BM * 8; i += 256) {
                int r = i >> 3, c = (i & 7) * 8;
                float2 st = stats[m0 + r];
                const float* src = Af + (size_t)(m0 + r) * K + k0 + c;
                float4 v0 = *(const float4*)src;
                float4 v1 = *(const float4*)(src + 4);
                float4 g0 = *(const float4*)(lng + k0 + c);
                float4 g1 = *(const float4*)(lng + k0 + c + 4);
                float4 b0 = *(const float4*)(lnb + k0 + c);
                float4 b1 = *(const float4*)(lnb + k0 + c + 4);
                short8 o;
                o[0] = f2bf((v0.x - st.x) * st.y * g0.x + b0.x);
                o[1] = f2bf((v0.y - st.x) * st.y * g0.y + b0.y);
                o[2] = f2bf((v0.z - st.x) * st.y * g0.z + b0.z);
                o[3] = f2bf((v0.w - st.x) * st.y * g0.w + b0.w);
                o[4] = f2bf((v1.x - st.x) * st.y * g1.x + b1.x);
                o[5] = f2bf((v1.y - st.x) * st.y * g1.y + b1.y);
                o[6] = f2bf((v1.z - st.x) * st.y * g1.z + b1.z);
                o[7] = f2bf((v1.w - st.x) * st.y * g1.w + b1.w);
                *(short8*)&As[r * LDT + c] = o;
            }
        } else {
            const short* Ab = (const short*)Av;
#pragma unroll
            for (int i = tid; i < BM * 8; i += 256) {
                int r = i >> 3, c = (i & 7) * 8;
                *(short8*)&As[r * LDT + c] = *(const short8*)&Ab[(size_t)(m0 + r) * K + k0 + c];
            }
        }
#pragma unroll
        for (int i = tid; i < BN * 8; i += 256) {
            int r = i >> 3, c = (i & 7) * 8;
            *(short8*)&Bs[r * LDT + c] = *(const short8*)&Bt[(size_t)(n0 + r) * K + k0 + c];
        }
        __syncthreads();
#pragma unroll
        for (int kk = 0; kk < 4; kk++) {
            short8 a[MR], b[NR];
#pragma unroll
            for (int i = 0; i < MR; i++)
                a[i] = *(const short8*)&As[(wr * WM + i * 32 + l31) * LDT + kk * 16 + hk];
#pragma unroll
            for (int j = 0; j < NR; j++)
                b[j] = *(const short8*)&Bs[(wc * WN + j * 32 + l31) * LDT + kk * 16 + hk];
#pragma unroll
            for (int i = 0; i < MR; i++)
#pragma unroll
                for (int j = 0; j < NR; j++)
                    acc[i][j] = __builtin_amdgcn_mfma_f32_32x32x16_bf16(a[i], b[j], acc[i][j], 0, 0, 0);
        }
    }
    int rbase = 4 * (lane >> 5);
    int bi = m0 >> 11;   // batch index
#pragma unroll
    for (int i = 0; i < MR; i++)
#pragma unroll
        for (int j = 0; j < NR; j++) {
            int col = n0 + wc * WN + j * 32 + l31;
            float gm = 1.f, bt = 0.f;
            if (FILM) {
                gm = gamma[bi * D_ + col];
                bt = beta[bi * D_ + col];
            }
#pragma unroll
            for (int r = 0; r < 16; r++) {
                int row = m0 + wr * WM + i * 32 + rbase + (r & 3) + 8 * (r >> 2);
                float v = acc[i][j][r];
                if (FILM) v = gm * v + bt;
                C[(size_t)row * N + col] = v;
            }
        }
}

// ---------------- depthwise causal conv (K=4) + SiLU ----------------
__global__ __launch_bounds__(256) void conv_silu_kernel(const float* __restrict__ xz,
                                                        const float* __restrict__ cw,
                                                        const float* __restrict__ cb,
                                                        float* __restrict__ uc) {
    int idx = blockIdx.x * 256 + threadIdx.x;  // over B*N*E
    int e = idx & (E_ - 1);
    int bn = idx >> 10;
    int n = bn & (N_ - 1);
    const float4 w = *(const float4*)(cw + e * 4);
    const float* up = xz + (size_t)bn * (2 * E_) + e;
    float acc = cb[e];
    acc = fmaf(up[0], w.w, acc);
    if (n >= 1) acc = fmaf(up[-(ptrdiff_t)(2 * E_)], w.z, acc);
    if (n >= 2) acc = fmaf(up[-(ptrdiff_t)(4 * E_)], w.y, acc);
    if (n >= 3) acc = fmaf(up[-(ptrdiff_t)(6 * E_)], w.x, acc);
    float sig = 1.f / (1.f + __expf(-acc));
    uc[idx] = acc * sig;
}

// ---------------- x_proj: x_dbl = uc @ W_x  [4096,1024]@[1024,64] ----------------
__global__ __launch_bounds__(256) void xproj_kernel(const float* __restrict__ uc,
                                                    const float* __restrict__ Wx,
                                                    float* __restrict__ xdbl) {
    int row0 = blockIdx.x * 8;
    int tid = threadIdx.x;
    __shared__ __align__(16) float lds[8 * E_];
#pragma unroll
    for (int i = tid; i < 8 * E_ / 4; i += 256) {
        int r = i >> 8;
        int c4 = (i & 255) * 4;
        *(float4*)&lds[r * E_ + c4] = *(const float4*)(uc + (size_t)(row0 + r) * E_ + c4);
    }
    __syncthreads();
    int c = tid & 63;
    int rr = tid >> 6;
    float a0 = 0.f, a1 = 0.f;
#pragma unroll 4
    for (int k = 0; k < E_; k++) {
        float w = Wx[k * 64 + c];
        a0 = fmaf(lds[rr * E_ + k], w, a0);
        a1 = fmaf(lds[(rr + 4) * E_ + k], w, a1);
    }
    xdbl[(size_t)(row0 + rr) * 64 + c] = a0;
    xdbl[(size_t)(row0 + rr + 4) * 64 + c] = a1;
}

// ---------------- delta = softplus(dt @ W_dt + b_dt)  K=32 ----------------
__global__ __launch_bounds__(256) void dt_kernel(const float* __restrict__ xdbl,
                                                 const float* __restrict__ Wdt,
                                                 const float* __restrict__ bdt,
                                                 float* __restrict__ delta) {
    int row0 = blockIdx.x * 8;
    int tid = threadIdx.x;
    __shared__ __align__(16) float dts[8 * 32];
    if (tid < 64) {
        int r = tid >> 3, c4 = (tid & 7) * 4;
        *(float4*)&dts[r * 32 + c4] = *(const float4*)(xdbl + (size_t)(row0 + r) * 64 + c4);
    }
    __syncthreads();
    float b4[4];
#pragma unroll
    for (int j = 0; j < 4; j++) b4[j] = bdt[tid + j * 256];
    float acc[8][4];
#pragma unroll
    for (int r = 0; r < 8; r++)
#pragma unroll
        for (int j = 0; j < 4; j++) acc[r][j] = 0.f;
#pragma unroll 4
    for (int k = 0; k < R_; k++) {
        float w[4];
#pragma unroll
        for (int j = 0; j < 4; j++) w[j] = Wdt[k * E_ + tid + j * 256];
#pragma unroll
        for (int r = 0; r < 8; r++) {
            float dv = dts[r * 32 + k];
#pragma unroll
            for (int j = 0; j < 4; j++) acc[r][j] = fmaf(dv, w[j], acc[r][j]);
        }
    }
#pragma unroll
    for (int r = 0; r < 8; r++)
#pragma unroll
        for (int j = 0; j < 4; j++) {
            float xv = acc[r][j] + b4[j];
            float sp = (xv > 20.f) ? xv : log1pf(__expf(xv));
            delta[(size_t)(row0 + r) * E_ + tid + j * 256] = sp;
        }
}

// ---------------- FiLM gamma/beta (parallel): 8 blocks x (64 d, 4 k-slices) ----------------
__global__ __launch_bounds__(256) void film2_kernel(const float* __restrict__ cond,
                                                    const float* __restrict__ gw,
                                                    const float* __restrict__ gb,
                                                    const float* __restrict__ bw,
                                                    const float* __restrict__ bb,
                                                    float* __restrict__ gamma,
                                                    float* __restrict__ beta) {
    __shared__ float cs[2][C_];
    __shared__ float red[4][64][4];
    int tid = threadIdx.x;
    int d0 = blockIdx.x * 64;
#pragma unroll
    for (int i = tid; i < 2 * C_ / 4; i += 256) {
        int b = i >> 7;
        int c4 = (i & 127) * 4;
        *(float4*)&cs[b][c4] = *(const float4*)(cond + (size_t)b * C_ + c4);
    }
    __syncthreads();
    int dl = tid & 63, ks = tid >> 6;
    int d = d0 + dl;
    float g0 = 0.f, g1 = 0.f, bt0 = 0.f, bt1 = 0.f;
#pragma unroll 4
    for (int k = ks * 128; k < ks * 128 + 128; k++) {
        float wg = gw[(size_t)k * D_ + d];
        float wb = bw[(size_t)k * D_ + d];
        float c0 = cs[0][k], c1 = cs[1][k];
        g0 = fmaf(c0, wg, g0);
        g1 = fmaf(c1, wg, g1);
        bt0 = fmaf(c0, wb, bt0);
        bt1 = fmaf(c1, wb, bt1);
    }
    red[ks][dl][0] = g0; red[ks][dl][1] = g1;
    red[ks][dl][2] = bt0; red[ks][dl][3] = bt1;
    __syncthreads();
    if (ks == 0) {
        float s0 = 0.f, s1 = 0.f, s2 = 0.f, s3 = 0.f;
#pragma unroll
        for (int q = 0; q < 4; q++) {
            s0 += red[q][dl][0]; s1 += red[q][dl][1];
            s2 += red[q][dl][2]; s3 += red[q][dl][3];
        }
        float gbv = gb[d], bbv = bb[d];
        gamma[d] = s0 + gbv;
        gamma[D_ + d] = s1 + gbv;
        beta[d] = s2 + bbv;
        beta[D_ + d] = s3 + bbv;
    }
}

// ---------------- chunked selective scan, s-in-registers ----------------
// phase1: local scan from h=0 per chunk; store hend[b][c][s][e] and cumdelta[b][c][e].
__global__ __launch_bounds__(256) void scan_p1(const float* __restrict__ delta,
                                               const float* __restrict__ uc,
                                               const float* __restrict__ xdbl,
                                               const float* __restrict__ A_log,
                                               float* __restrict__ hend,
                                               float* __restrict__ cumd) {
    int blk = blockIdx.x;            // b*(NC_*4) + c*4 + eq
    int eq = blk & 3;
    int c = (blk >> 2) & (NC_ - 1);
    int b = blk >> 8;
    int tid = threadIdx.x;
    int e = eq * 256 + tid;
    __shared__ float Bsl[CH_][16];
    int base = (b * N_ + c * CH_) * 64;
    for (int i = tid; i < CH_ * 16; i += 256) {
        int n = i >> 4, col = i & 15;
        Bsl[n][col] = xdbl[base + n * 64 + R_ + col];
    }
    float Aes[16];
    const float4* al = (const float4*)(A_log + e * 16);
#pragma unroll
    for (int j = 0; j < 4; j++) {
        float4 a = al[j];
        Aes[j * 4 + 0] = -__expf(a.x);
        Aes[j * 4 + 1] = -__expf(a.y);
        Aes[j * 4 + 2] = -__expf(a.z);
        Aes[j * 4 + 3] = -__expf(a.w);
    }
    __syncthreads();
    float h[16];
#pragma unroll
    for (int s = 0; s < 16; s++) h[s] = 0.f;
    float cum = 0.f;
    const float* dp = delta + (size_t)(b * N_ + c * CH_) * E_ + e;
    const float* up = uc + (size_t)(b * N_ + c * CH_) * E_ + e;
#pragma unroll 2
    for (int n = 0; n < CH_; n++) {
        float dv = dp[n * E_];
        float uv = up[n * E_];
        float du = dv * uv;
        cum += dv;
        float Bl[16];
#pragma unroll
        for (int j = 0; j < 4; j++) *(float4*)&Bl[j * 4] = *(const float4*)&Bsl[n][j * 4];
#pragma unroll
        for (int s = 0; s < 16; s++) {
            float dA = __expf(dv * Aes[s]);
            h[s] = fmaf(dA, h[s], du * Bl[s]);
        }
    }
    size_t ob = (size_t)(b * NC_ + c) * 16 * E_ + e;
#pragma unroll
    for (int s = 0; s < 16; s++) hend[ob + (size_t)s * E_] = h[s];
    cumd[(size_t)(b * NC_ + c) * E_ + e] = cum;
}

// combine: transform hend in place into chunk-entry states (P rebuilt from cumdelta).
__global__ __launch_bounds__(256) void scan_comb(float* __restrict__ hend,
                                                 const float* __restrict__ cumd,
                                                 const float* __restrict__ A_log) {
    int idx = blockIdx.x * 256 + threadIdx.x;   // over B*S*E = 32768
    int b = idx >> 14;
    int s = (idx >> 10) & 15;
    int e = idx & 1023;
    float Aes = -__expf(A_log[e * 16 + s]);
    float h = 0.f;
#pragma unroll 4
    for (int c = 0; c < NC_; c++) {
        size_t i = ((size_t)((b * NC_ + c) * 16) + s) * E_ + e;
        float he = hend[i];
        float P = __expf(Aes * cumd[(size_t)(b * NC_ + c) * E_ + e]);
        hend[i] = h;
        h = fmaf(P, h, he);
    }
}

// phase3: local scan seeded with hend (entry states); produce gated y as bf16.
__global__ __launch_bounds__(256) void scan_p3(const float* __restrict__ delta,
                                               const float* __restrict__ uc,
                                               const float* __restrict__ xdbl,
                                               const float* __restrict__ xz,
                                               const float* __restrict__ A_log,
                                               const float* __restrict__ D_skip,
                                               const float* __restrict__ hend,
                                               short* __restrict__ yb) {
    int blk = blockIdx.x;
    int eq = blk & 3;
    int c = (blk >> 2) & (NC_ - 1);
    int b = blk >> 8;
    int tid = threadIdx.x;
    int e = eq * 256 + tid;
    __shared__ float Bsl[CH_][16];
    __shared__ float Csl[CH_][16];
    int base = (b * N_ + c * CH_) * 64;
    for (int i = tid; i < CH_ * 32; i += 256) {
        int n = i >> 5, col = i & 31;
        float v = xdbl[base + n * 64 + R_ + col];
        if (col < 16) Bsl[n][col] = v;
        else Csl[n][col - 16] = v;
    }
    float Aes[16];
    const float4* al = (const float4*)(A_log + e * 16);
#pragma unroll
    for (int j = 0; j < 4; j++) {
        float4 a = al[j];
        Aes[j * 4 + 0] = -__expf(a.x);
        Aes[j * 4 + 1] = -__expf(a.y);
        Aes[j * 4 + 2] = -__expf(a.z);
        Aes[j * 4 + 3] = -__expf(a.w);
    }
    float dsk = D_skip[e];
    float h[16];
    size_t ob = (size_t)(b * NC_ + c) * 16 * E_ + e;
#pragma unroll
    for (int s = 0; s < 16; s++) h[s] = hend[ob + (size_t)s * E_];
    __syncthreads();
    const float* dp = delta + (size_t)(b * N_ + c * CH_) * E_ + e;
    const float* up = uc + (size_t)(b * N_ + c * CH_) * E_ + e;
    const float* zp = xz + (size_t)(b * N_ + c * CH_) * (2 * E_) + E_ + e;
    short* yp = yb + (size_t)(b * N_ + c * CH_) * E_ + e;
#pragma unroll 2
    for (int n = 0; n < CH_; n++) {
        float dv = dp[n * E_];
        float uv = up[n * E_];
        float du = dv * uv;
        float Bl[16], Cl[16];
#pragma unroll
        for (int j = 0; j < 4; j++) {
            *(float4*)&Bl[j * 4] = *(const float4*)&Bsl[n][j * 4];
            *(float4*)&Cl[j * 4] = *(const float4*)&Csl[n][j * 4];
        }
        float y = 0.f;
#pragma unroll
        for (int s = 0; s < 16; s++) {
            float dA = __expf(dv * Aes[s]);
            h[s] = fmaf(dA, h[s], du * Bl[s]);
            y = fmaf(h[s], Cl[s], y);
        }
        float zv = zp[n * 2 * E_];
        float yy = y + dsk * uv;
        yy = yy * (zv / (1.f + __expf(-zv)));
        yp[n * E_] = f2bf(yy);
    }
}

extern "C" void kernel_launch(void* const* d_in, const int* in_sizes, int n_in,
                              void* d_out, int out_size, void* d_ws, size_t ws_size,
                              hipStream_t stream) {
    const float* x       = (const float*)d_in[0];
    const float* cond    = (const float*)d_in[1];
    const float* ln_g    = (const float*)d_in[2];
    const float* ln_b    = (const float*)d_in[3];
    const float* W_in    = (const float*)d_in[4];
    const float* conv_w  = (const float*)d_in[5];
    const float* conv_b  = (const float*)d_in[6];
    const float* W_x     = (const float*)d_in[7];
    const float* W_dt    = (const float*)d_in[8];
    const float* b_dt    = (const float*)d_in[9];
    const float* A_log   = (const float*)d_in[10];
    const float* D_skip  = (const float*)d_in[11];
    const float* W_out   = (const float*)d_in[12];
    const float* film_gw = (const float*)d_in[13];
    const float* film_gb = (const float*)d_in[14];
    const float* film_bw = (const float*)d_in[15];
    const float* film_bb = (const float*)d_in[16];
    float* out = (float*)d_out;

    float* ws = (float*)d_ws;
    float* xz    = ws;                       // 8,388,608 f
    float* ucb   = xz + 8388608;             // 4,194,304 f
    float* xdbl  = ucb + 4194304;            //   262,144 f
    float* delta = xdbl + 262144;            // 4,194,304 f
    float* gamma = delta + 4194304;          //     1,024 f
    float* beta  = gamma + 1024;             //     1,024 f
    float2* stats = (float2*)(beta + 1024);  //     4,096 f2
    float* hend  = (float*)(stats + 4096);   // 2,097,152 f  (B*NC*S*E)
    float* cumd  = hend + 2097152;           //   131,072 f  (B*NC*E)
    short* Wint  = (short*)(cumd + 131072);  // 1,048,576 sh
    short* Woutt = Wint + 1048576;           //   524,288 sh
    short* yb    = Woutt + 524288;           // 4,194,304 sh

    ln_stats_kernel<<<B_ * N_, 256, 0, stream>>>(x, stats);
    transpose_bf16_kernel<<<dim3(2 * E_ / 32, D_ / 32), 256, 0, stream>>>(W_in, Wint, D_, 2 * E_);
    transpose_bf16_kernel<<<dim3(D_ / 32, E_ / 32), 256, 0, stream>>>(W_out, Woutt, E_, D_);
    film2_kernel<<<D_ / 64, 256, 0, stream>>>(cond, film_gw, film_gb, film_bw, film_bb, gamma, beta);

    // xz = LN(x) @ W_in   [4096,512]x[512,2048], LN fused into A staging
    gemm_bf16<128, 128, false, true>
        <<<dim3(2 * E_ / 128, B_ * N_ / 128), 256, 0, stream>>>(
            x, Wint, xz, B_ * N_, 2 * E_, D_, stats, ln_g, ln_b, nullptr, nullptr);

    conv_silu_kernel<<<(B_ * N_ * E_) / 256, 256, 0, stream>>>(xz, conv_w, conv_b, ucb);

    xproj_kernel<<<(B_ * N_) / 8, 256, 0, stream>>>(ucb, W_x, xdbl);

    dt_kernel<<<(B_ * N_) / 8, 256, 0, stream>>>(xdbl, W_dt, b_dt, delta);

    scan_p1<<<B_ * NC_ * 4, 256, 0, stream>>>(delta, ucb, xdbl, A_log, hend, cumd);
    scan_comb<<<(B_ * S_ * E_) / 256, 256, 0, stream>>>(hend, cumd, A_log);
    scan_p3<<<B_ * NC_ * 4, 256, 0, stream>>>(delta, ucb, xdbl, xz, A_log, D_skip, hend, yb);

    // out = FiLM(y @ W_out)   [4096,1024]x[1024,512]
    gemm_bf16<128, 64, true, false>
        <<<dim3(D_ / 64, B_ * N_ / 128), 256, 0, stream>>>(
            yb, Woutt, out, B_ * N_, D_, E_, nullptr, nullptr, nullptr, gamma, beta);
}

// Round 5
// 219.695 us; speedup vs baseline: 8.8787x; 1.1839x over previous
//
#include <hip/hip_runtime.h>
#include <hip/hip_bf16.h>
#include <math.h>

#define B_ 2
#define N_ 2048
#define D_ 512
#define E_ 1024
#define S_ 16
#define KC_ 4
#define R_ 32
#define C_ 512
#define CH_ 32
#define NC_ (N_ / CH_)   // 64 chunks

using short8 = __attribute__((ext_vector_type(8))) short;
using f32x16 = __attribute__((ext_vector_type(16))) float;

__device__ __forceinline__ short f2bf(float f) {
    union { float f; unsigned u; } x; x.f = f;
    unsigned r = (x.u + 0x7fffu + ((x.u >> 16) & 1u)) >> 16;
    return (short)r;
}

// ---------------- LayerNorm stats (mu, rsqrt(var+eps)) per token ----------------
__global__ __launch_bounds__(256) void ln_stats_kernel(const float* __restrict__ x,
                                                       float2* __restrict__ stats) {
    int t = blockIdx.x;
    int tid = threadIdx.x;
    float2 v = *(const float2*)(x + (size_t)t * D_ + tid * 2);
    float s = v.x + v.y;
    float s2 = fmaf(v.x, v.x, v.y * v.y);
#pragma unroll
    for (int o = 32; o >= 1; o >>= 1) {
        s += __shfl_down(s, o);
        s2 += __shfl_down(s2, o);
    }
    __shared__ float red[8];
    int wid = tid >> 6;
    if ((tid & 63) == 0) { red[wid] = s; red[4 + wid] = s2; }
    __syncthreads();
    if (tid == 0) {
        float sum = red[0] + red[1] + red[2] + red[3];
        float sum2 = red[4] + red[5] + red[6] + red[7];
        float mu = sum * (1.f / (float)D_);
        float var = sum2 * (1.f / (float)D_) - mu * mu;
        stats[t] = make_float2(mu, rsqrtf(var + 1e-5f));
    }
}

// ---------------- transpose fp32 [K][N] -> bf16 [N][K] ----------------
__global__ __launch_bounds__(256) void transpose_bf16_kernel(const float* __restrict__ W,
                                                             short* __restrict__ Wt,
                                                             int K, int N) {
    __shared__ float t[32][33];
    int n0 = blockIdx.x * 32, k0 = blockIdx.y * 32;
    int c = threadIdx.x & 31, r = threadIdx.x >> 5;
#pragma unroll
    for (int rr = r; rr < 32; rr += 8)
        t[rr][c] = W[(size_t)(k0 + rr) * N + n0 + c];
    __syncthreads();
#pragma unroll
    for (int rr = r; rr < 32; rr += 8)
        Wt[(size_t)(n0 + rr) * K + k0 + c] = f2bf(t[c][rr]);
}

// ---------------- bf16 MFMA GEMM: C[M][N] = A[M][K] * Bt[N][K]^T ----------------
// LNA: A is fp32, LayerNorm applied during staging. FILM: fused gamma/beta epilogue.
template <int BM, int BN, bool FILM, bool LNA>
__global__ __launch_bounds__(256) void gemm_bf16(
    const void* __restrict__ Av, const short* __restrict__ Bt, float* __restrict__ C,
    int M, int N, int K,
    const float2* __restrict__ stats, const float* __restrict__ lng, const float* __restrict__ lnb,
    const float* __restrict__ gamma, const float* __restrict__ beta) {
    constexpr int BK = 64;
    constexpr int LDT = BK + 8;          // 72 shorts = 144B pitch
    constexpr int WM = BM / 2, WN = BN / 2;
    constexpr int MR = WM / 32, NR = WN / 32;
    __shared__ __align__(16) short As[BM * LDT];
    __shared__ __align__(16) short Bs[BN * LDT];
    int tid = threadIdx.x;
    int lane = tid & 63, w = tid >> 6;
    int wr = w >> 1, wc = w & 1;
    int m0 = blockIdx.y * BM, n0 = blockIdx.x * BN;

    f32x16 acc[MR][NR];
#pragma unroll
    for (int i = 0; i < MR; i++)
#pragma unroll
        for (int j = 0; j < NR; j++)
#pragma unroll
            for (int r = 0; r < 16; r++) acc[i][j][r] = 0.f;

    int l31 = lane & 31, hk = (lane >> 5) * 8;

    for (int k0 = 0; k0 < K; k0 += BK) {
        __syncthreads();
        if constexpr (LNA) {
            const float* Af = (const float*)Av;
#pragma unroll
            for (int i = tid; i < BM * 8; i += 256) {
                int r = i >> 3, c = (i & 7) * 8;
                float2 st = stats[m0 + r];
                const float* src = Af + (size_t)(m0 + r) * K + k0 + c;
                float4 v0 = *(const float4*)src;
                float4 v1 = *(const float4*)(src + 4);
                float4 g0 = *(const float4*)(lng + k0 + c);
                float4 g1 = *(const float4*)(lng + k0 + c + 4);
                float4 b0 = *(const float4*)(lnb + k0 + c);
                float4 b1 = *(const float4*)(lnb + k0 + c + 4);
                short8 o;
                o[0] = f2bf((v0.x - st.x) * st.y * g0.x + b0.x);
                o[1] = f2bf((v0.y - st.x) * st.y * g0.y + b0.y);
                o[2] = f2bf((v0.z - st.x) * st.y * g0.z + b0.z);
                o[3] = f2bf((v0.w - st.x) * st.y * g0.w + b0.w);
                o[4] = f2bf((v1.x - st.x) * st.y * g1.x + b1.x);
                o[5] = f2bf((v1.y - st.x) * st.y * g1.y + b1.y);
                o[6] = f2bf((v1.z - st.x) * st.y * g1.z + b1.z);
                o[7] = f2bf((v1.w - st.x) * st.y * g1.w + b1.w);
                *(short8*)&As[r * LDT + c] = o;
            }
        } else {
            const short* Ab = (const short*)Av;
#pragma unroll
            for (int i = tid; i < BM * 8; i += 256) {
                int r = i >> 3, c = (i & 7) * 8;
                *(short8*)&As[r * LDT + c] = *(const short8*)&Ab[(size_t)(m0 + r) * K + k0 + c];
            }
        }
#pragma unroll
        for (int i = tid; i < BN * 8; i += 256) {
            int r = i >> 3, c = (i & 7) * 8;
            *(short8*)&Bs[r * LDT + c] = *(const short8*)&Bt[(size_t)(n0 + r) * K + k0 + c];
        }
        __syncthreads();
#pragma unroll
        for (int kk = 0; kk < 4; kk++) {
            short8 a[MR], b[NR];
#pragma unroll
            for (int i = 0; i < MR; i++)
                a[i] = *(const short8*)&As[(wr * WM + i * 32 + l31) * LDT + kk * 16 + hk];
#pragma unroll
            for (int j = 0; j < NR; j++)
                b[j] = *(const short8*)&Bs[(wc * WN + j * 32 + l31) * LDT + kk * 16 + hk];
#pragma unroll
            for (int i = 0; i < MR; i++)
#pragma unroll
                for (int j = 0; j < NR; j++)
                    acc[i][j] = __builtin_amdgcn_mfma_f32_32x32x16_bf16(a[i], b[j], acc[i][j], 0, 0, 0);
        }
    }
    int rbase = 4 * (lane >> 5);
    int bi = m0 >> 11;   // batch index
#pragma unroll
    for (int i = 0; i < MR; i++)
#pragma unroll
        for (int j = 0; j < NR; j++) {
            int col = n0 + wc * WN + j * 32 + l31;
            float gm = 1.f, bt = 0.f;
            if (FILM) {
                gm = gamma[bi * D_ + col];
                bt = beta[bi * D_ + col];
            }
#pragma unroll
            for (int r = 0; r < 16; r++) {
                int row = m0 + wr * WM + i * 32 + rbase + (r & 3) + 8 * (r >> 2);
                float v = acc[i][j][r];
                if (FILM) v = gm * v + bt;
                C[(size_t)row * N + col] = v;
            }
        }
}

// ---------------- depthwise causal conv (K=4) + SiLU; dual fp32/bf16 output ----------------
__global__ __launch_bounds__(256) void conv_silu_kernel(const float* __restrict__ xz,
                                                        const float* __restrict__ cw,
                                                        const float* __restrict__ cb,
                                                        float* __restrict__ uc,
                                                        short* __restrict__ ucb16) {
    int idx = blockIdx.x * 256 + threadIdx.x;  // over B*N*E
    int e = idx & (E_ - 1);
    int bn = idx >> 10;
    int n = bn & (N_ - 1);
    const float4 w = *(const float4*)(cw + e * 4);
    const float* up = xz + (size_t)bn * (2 * E_) + e;
    float acc = cb[e];
    acc = fmaf(up[0], w.w, acc);
    if (n >= 1) acc = fmaf(up[-(ptrdiff_t)(2 * E_)], w.z, acc);
    if (n >= 2) acc = fmaf(up[-(ptrdiff_t)(4 * E_)], w.y, acc);
    if (n >= 3) acc = fmaf(up[-(ptrdiff_t)(6 * E_)], w.x, acc);
    float sig = 1.f / (1.f + __expf(-acc));
    float v = acc * sig;
    uc[idx] = v;
    ucb16[idx] = f2bf(v);
}

// ---------------- delta = softplus(dt @ W_dt + b_dt)  K=32 ----------------
__global__ __launch_bounds__(256) void dt_kernel(const float* __restrict__ xdbl,
                                                 const float* __restrict__ Wdt,
                                                 const float* __restrict__ bdt,
                                                 float* __restrict__ delta) {
    int row0 = blockIdx.x * 8;
    int tid = threadIdx.x;
    __shared__ __align__(16) float dts[8 * 32];
    if (tid < 64) {
        int r = tid >> 3, c4 = (tid & 7) * 4;
        *(float4*)&dts[r * 32 + c4] = *(const float4*)(xdbl + (size_t)(row0 + r) * 64 + c4);
    }
    __syncthreads();
    float b4[4];
#pragma unroll
    for (int j = 0; j < 4; j++) b4[j] = bdt[tid + j * 256];
    float acc[8][4];
#pragma unroll
    for (int r = 0; r < 8; r++)
#pragma unroll
        for (int j = 0; j < 4; j++) acc[r][j] = 0.f;
#pragma unroll 4
    for (int k = 0; k < R_; k++) {
        float w[4];
#pragma unroll
        for (int j = 0; j < 4; j++) w[j] = Wdt[k * E_ + tid + j * 256];
#pragma unroll
        for (int r = 0; r < 8; r++) {
            float dv = dts[r * 32 + k];
#pragma unroll
            for (int j = 0; j < 4; j++) acc[r][j] = fmaf(dv, w[j], acc[r][j]);
        }
    }
#pragma unroll
    for (int r = 0; r < 8; r++)
#pragma unroll
        for (int j = 0; j < 4; j++) {
            float xv = acc[r][j] + b4[j];
            float sp = (xv > 20.f) ? xv : log1pf(__expf(xv));
            delta[(size_t)(row0 + r) * E_ + tid + j * 256] = sp;
        }
}

// ---------------- FiLM gamma/beta (parallel): 8 blocks x (64 d, 4 k-slices) ----------------
__global__ __launch_bounds__(256) void film2_kernel(const float* __restrict__ cond,
                                                    const float* __restrict__ gw,
                                                    const float* __restrict__ gb,
                                                    const float* __restrict__ bw,
                                                    const float* __restrict__ bb,
                                                    float* __restrict__ gamma,
                                                    float* __restrict__ beta) {
    __shared__ float cs[2][C_];
    __shared__ float red[4][64][4];
    int tid = threadIdx.x;
    int d0 = blockIdx.x * 64;
#pragma unroll
    for (int i = tid; i < 2 * C_ / 4; i += 256) {
        int b = i >> 7;
        int c4 = (i & 127) * 4;
        *(float4*)&cs[b][c4] = *(const float4*)(cond + (size_t)b * C_ + c4);
    }
    __syncthreads();
    int dl = tid & 63, ks = tid >> 6;
    int d = d0 + dl;
    float g0 = 0.f, g1 = 0.f, bt0 = 0.f, bt1 = 0.f;
#pragma unroll 4
    for (int k = ks * 128; k < ks * 128 + 128; k++) {
        float wg = gw[(size_t)k * D_ + d];
        float wb = bw[(size_t)k * D_ + d];
        float c0 = cs[0][k], c1 = cs[1][k];
        g0 = fmaf(c0, wg, g0);
        g1 = fmaf(c1, wg, g1);
        bt0 = fmaf(c0, wb, bt0);
        bt1 = fmaf(c1, wb, bt1);
    }
    red[ks][dl][0] = g0; red[ks][dl][1] = g1;
    red[ks][dl][2] = bt0; red[ks][dl][3] = bt1;
    __syncthreads();
    if (ks == 0) {
        float s0 = 0.f, s1 = 0.f, s2 = 0.f, s3 = 0.f;
#pragma unroll
        for (int q = 0; q < 4; q++) {
            s0 += red[q][dl][0]; s1 += red[q][dl][1];
            s2 += red[q][dl][2]; s3 += red[q][dl][3];
        }
        float gbv = gb[d], bbv = bb[d];
        gamma[d] = s0 + gbv;
        gamma[D_ + d] = s1 + gbv;
        beta[d] = s2 + bbv;
        beta[D_ + d] = s3 + bbv;
    }
}

// ---------------- chunked selective scan, s-in-registers ----------------
__global__ __launch_bounds__(256) void scan_p1(const float* __restrict__ delta,
                                               const float* __restrict__ uc,
                                               const float* __restrict__ xdbl,
                                               const float* __restrict__ A_log,
                                               float* __restrict__ hend,
                                               float* __restrict__ cumd) {
    int blk = blockIdx.x;            // b*(NC_*4) + c*4 + eq
    int eq = blk & 3;
    int c = (blk >> 2) & (NC_ - 1);
    int b = blk >> 8;
    int tid = threadIdx.x;
    int e = eq * 256 + tid;
    __shared__ float Bsl[CH_][16];
    int base = (b * N_ + c * CH_) * 64;
    for (int i = tid; i < CH_ * 16; i += 256) {
        int n = i >> 4, col = i & 15;
        Bsl[n][col] = xdbl[base + n * 64 + R_ + col];
    }
    float Aes[16];
    const float4* al = (const float4*)(A_log + e * 16);
#pragma unroll
    for (int j = 0; j < 4; j++) {
        float4 a = al[j];
        Aes[j * 4 + 0] = -__expf(a.x);
        Aes[j * 4 + 1] = -__expf(a.y);
        Aes[j * 4 + 2] = -__expf(a.z);
        Aes[j * 4 + 3] = -__expf(a.w);
    }
    __syncthreads();
    float h[16];
#pragma unroll
    for (int s = 0; s < 16; s++) h[s] = 0.f;
    float cum = 0.f;
    const float* dp = delta + (size_t)(b * N_ + c * CH_) * E_ + e;
    const float* up = uc + (size_t)(b * N_ + c * CH_) * E_ + e;
#pragma unroll 2
    for (int n = 0; n < CH_; n++) {
        float dv = dp[n * E_];
        float uv = up[n * E_];
        float du = dv * uv;
        cum += dv;
        float Bl[16];
#pragma unroll
        for (int j = 0; j < 4; j++) *(float4*)&Bl[j * 4] = *(const float4*)&Bsl[n][j * 4];
#pragma unroll
        for (int s = 0; s < 16; s++) {
            float dA = __expf(dv * Aes[s]);
            h[s] = fmaf(dA, h[s], du * Bl[s]);
        }
    }
    size_t ob = (size_t)(b * NC_ + c) * 16 * E_ + e;
#pragma unroll
    for (int s = 0; s < 16; s++) hend[ob + (size_t)s * E_] = h[s];
    cumd[(size_t)(b * NC_ + c) * E_ + e] = cum;
}

__global__ __launch_bounds__(256) void scan_comb(float* __restrict__ hend,
                                                 const float* __restrict__ cumd,
                                                 const float* __restrict__ A_log) {
    int idx = blockIdx.x * 256 + threadIdx.x;   // over B*S*E = 32768
    int b = idx >> 14;
    int s = (idx >> 10) & 15;
    int e = idx & 1023;
    float Aes = -__expf(A_log[e * 16 + s]);
    float h = 0.f;
#pragma unroll 4
    for (int c = 0; c < NC_; c++) {
        size_t i = ((size_t)((b * NC_ + c) * 16) + s) * E_ + e;
        float he = hend[i];
        float P = __expf(Aes * cumd[(size_t)(b * NC_ + c) * E_ + e]);
        hend[i] = h;
        h = fmaf(P, h, he);
    }
}

__global__ __launch_bounds__(256) void scan_p3(const float* __restrict__ delta,
                                               const float* __restrict__ uc,
                                               const float* __restrict__ xdbl,
                                               const float* __restrict__ xz,
                                               const float* __restrict__ A_log,
                                               const float* __restrict__ D_skip,
                                               const float* __restrict__ hend,
                                               short* __restrict__ yb) {
    int blk = blockIdx.x;
    int eq = blk & 3;
    int c = (blk >> 2) & (NC_ - 1);
    int b = blk >> 8;
    int tid = threadIdx.x;
    int e = eq * 256 + tid;
    __shared__ float Bsl[CH_][16];
    __shared__ float Csl[CH_][16];
    int base = (b * N_ + c * CH_) * 64;
    for (int i = tid; i < CH_ * 32; i += 256) {
        int n = i >> 5, col = i & 31;
        float v = xdbl[base + n * 64 + R_ + col];
        if (col < 16) Bsl[n][col] = v;
        else Csl[n][col - 16] = v;
    }
    float Aes[16];
    const float4* al = (const float4*)(A_log + e * 16);
#pragma unroll
    for (int j = 0; j < 4; j++) {
        float4 a = al[j];
        Aes[j * 4 + 0] = -__expf(a.x);
        Aes[j * 4 + 1] = -__expf(a.y);
        Aes[j * 4 + 2] = -__expf(a.z);
        Aes[j * 4 + 3] = -__expf(a.w);
    }
    float dsk = D_skip[e];
    float h[16];
    size_t ob = (size_t)(b * NC_ + c) * 16 * E_ + e;
#pragma unroll
    for (int s = 0; s < 16; s++) h[s] = hend[ob + (size_t)s * E_];
    __syncthreads();
    const float* dp = delta + (size_t)(b * N_ + c * CH_) * E_ + e;
    const float* up = uc + (size_t)(b * N_ + c * CH_) * E_ + e;
    const float* zp = xz + (size_t)(b * N_ + c * CH_) * (2 * E_) + E_ + e;
    short* yp = yb + (size_t)(b * N_ + c * CH_) * E_ + e;
#pragma unroll 2
    for (int n = 0; n < CH_; n++) {
        float dv = dp[n * E_];
        float uv = up[n * E_];
        float du = dv * uv;
        float Bl[16], Cl[16];
#pragma unroll
        for (int j = 0; j < 4; j++) {
            *(float4*)&Bl[j * 4] = *(const float4*)&Bsl[n][j * 4];
            *(float4*)&Cl[j * 4] = *(const float4*)&Csl[n][j * 4];
        }
        float y = 0.f;
#pragma unroll
        for (int s = 0; s < 16; s++) {
            float dA = __expf(dv * Aes[s]);
            h[s] = fmaf(dA, h[s], du * Bl[s]);
            y = fmaf(h[s], Cl[s], y);
        }
        float zv = zp[n * 2 * E_];
        float yy = y + dsk * uv;
        yy = yy * (zv / (1.f + __expf(-zv)));
        yp[n * E_] = f2bf(yy);
    }
}

extern "C" void kernel_launch(void* const* d_in, const int* in_sizes, int n_in,
                              void* d_out, int out_size, void* d_ws, size_t ws_size,
                              hipStream_t stream) {
    const float* x       = (const float*)d_in[0];
    const float* cond    = (const float*)d_in[1];
    const float* ln_g    = (const float*)d_in[2];
    const float* ln_b    = (const float*)d_in[3];
    const float* W_in    = (const float*)d_in[4];
    const float* conv_w  = (const float*)d_in[5];
    const float* conv_b  = (const float*)d_in[6];
    const float* W_x     = (const float*)d_in[7];
    const float* W_dt    = (const float*)d_in[8];
    const float* b_dt    = (const float*)d_in[9];
    const float* A_log   = (const float*)d_in[10];
    const float* D_skip  = (const float*)d_in[11];
    const float* W_out   = (const float*)d_in[12];
    const float* film_gw = (const float*)d_in[13];
    const float* film_gb = (const float*)d_in[14];
    const float* film_bw = (const float*)d_in[15];
    const float* film_bb = (const float*)d_in[16];
    float* out = (float*)d_out;

    float* ws = (float*)d_ws;
    float* xz    = ws;                       // 8,388,608 f
    float* ucb   = xz + 8388608;             // 4,194,304 f
    float* xdbl  = ucb + 4194304;            //   262,144 f
    float* delta = xdbl + 262144;            // 4,194,304 f
    float* gamma = delta + 4194304;          //     1,024 f
    float* beta  = gamma + 1024;             //     1,024 f
    float2* stats = (float2*)(beta + 1024);  //     4,096 f2
    float* hend  = (float*)(stats + 4096);   // 2,097,152 f  (B*NC*S*E)
    float* cumd  = hend + 2097152;           //   131,072 f  (B*NC*E)
    short* Wint  = (short*)(cumd + 131072);  // 1,048,576 sh
    short* Woutt = Wint + 1048576;           //   524,288 sh
    short* yb    = Woutt + 524288;           // 4,194,304 sh
    short* Wxt   = yb + 4194304;             //    65,536 sh (W_x^T bf16 [64][1024])
    short* ucb16 = yb;                       // alias: dead after xproj; yb written later by scan_p3

    ln_stats_kernel<<<B_ * N_, 256, 0, stream>>>(x, stats);
    transpose_bf16_kernel<<<dim3(2 * E_ / 32, D_ / 32), 256, 0, stream>>>(W_in, Wint, D_, 2 * E_);
    transpose_bf16_kernel<<<dim3(D_ / 32, E_ / 32), 256, 0, stream>>>(W_out, Woutt, E_, D_);
    transpose_bf16_kernel<<<dim3(64 / 32, E_ / 32), 256, 0, stream>>>(W_x, Wxt, E_, 64);
    film2_kernel<<<D_ / 64, 256, 0, stream>>>(cond, film_gw, film_gb, film_bw, film_bb, gamma, beta);

    // xz = LN(x) @ W_in   [4096,512]x[512,2048], LN fused into A staging
    gemm_bf16<128, 128, false, true>
        <<<dim3(2 * E_ / 128, B_ * N_ / 128), 256, 0, stream>>>(
            x, Wint, xz, B_ * N_, 2 * E_, D_, stats, ln_g, ln_b, nullptr, nullptr);

    conv_silu_kernel<<<(B_ * N_ * E_) / 256, 256, 0, stream>>>(xz, conv_w, conv_b, ucb, ucb16);

    // x_dbl = uc @ W_x   [4096,1024]x[1024,64] -> MFMA bf16, 64 blocks
    gemm_bf16<64, 64, false, false>
        <<<dim3(1, B_ * N_ / 64), 256, 0, stream>>>(
            ucb16, Wxt, xdbl, B_ * N_, 64, E_, nullptr, nullptr, nullptr, nullptr, nullptr);

    dt_kernel<<<(B_ * N_) / 8, 256, 0, stream>>>(xdbl, W_dt, b_dt, delta);

    scan_p1<<<B_ * NC_ * 4, 256, 0, stream>>>(delta, ucb, xdbl, A_log, hend, cumd);
    scan_comb<<<(B_ * S_ * E_) / 256, 256, 0, stream>>>(hend, cumd, A_log);
    scan_p3<<<B_ * NC_ * 4, 256, 0, stream>>>(delta, ucb, xdbl, xz, A_log, D_skip, hend, yb);

    // out = FiLM(y @ W_out)   [4096,1024]x[1024,512]
    gemm_bf16<128, 64, true, false>
        <<<dim3(D_ / 64, B_ * N_ / 128), 256, 0, stream>>>(
            yb, Woutt, out, B_ * N_, D_, E_, nullptr, nullptr, nullptr, gamma, beta);
}

// Round 6
// 178.815 us; speedup vs baseline: 10.9085x; 1.2286x over previous
//
#include <hip/hip_runtime.h>
#include <hip/hip_bf16.h>
#include <math.h>

#define B_ 2
#define N_ 2048
#define D_ 512
#define E_ 1024
#define S_ 16
#define KC_ 4
#define R_ 32
#define C_ 512
#define CH_ 32
#define NC_ (N_ / CH_)   // 64 chunks

using short8 = __attribute__((ext_vector_type(8))) short;
using f32x4  = __attribute__((ext_vector_type(4))) float;
using f32x16 = __attribute__((ext_vector_type(16))) float;

__device__ __forceinline__ short f2bf(float f) {
    union { float f; unsigned u; } x; x.f = f;
    unsigned r = (x.u + 0x7fffu + ((x.u >> 16) & 1u)) >> 16;
    return (short)r;
}
__device__ __forceinline__ float bf2f(short s) {
    union { unsigned u; float f; } x;
    x.u = ((unsigned)(unsigned short)s) << 16;
    return x.f;
}

// ================= prep: film2 | 4 transposes | ln_stats, one launch =================
// block ranges: [0,8) film2; [8,1032) W_in^T; [1032,1544) W_out^T;
//               [1544,1608) W_x^T; [1608,1640) W_dt^T; [1640,5736) ln_stats
__global__ __launch_bounds__(256) void prep_kernel(
    const float* __restrict__ x, float2* __restrict__ stats,
    const float* __restrict__ W_in, short* __restrict__ Wint,
    const float* __restrict__ W_out, short* __restrict__ Woutt,
    const float* __restrict__ W_x, short* __restrict__ Wxt,
    const float* __restrict__ W_dt, short* __restrict__ Wdtt,
    const float* __restrict__ cond,
    const float* __restrict__ gw, const float* __restrict__ gb,
    const float* __restrict__ bw, const float* __restrict__ bb,
    float* __restrict__ gamma, float* __restrict__ beta) {
    __shared__ __align__(16) float smem[2112];   // 8448 B, reused per job
    int bid = blockIdx.x;
    int tid = threadIdx.x;
    if (bid < 8) {
        // ---- film2: d0 = bid*64 ----
        float* cs = smem;            // [2][512]
        float* red = smem + 1024;    // [4][64][4]
        int d0 = bid * 64;
#pragma unroll
        for (int i = tid; i < 2 * C_ / 4; i += 256) {
            int b = i >> 7;
            int c4 = (i & 127) * 4;
            *(float4*)&cs[b * C_ + c4] = *(const float4*)(cond + (size_t)b * C_ + c4);
        }
        __syncthreads();
        int dl = tid & 63, ks = tid >> 6;
        int d = d0 + dl;
        float g0 = 0.f, g1 = 0.f, bt0 = 0.f, bt1 = 0.f;
#pragma unroll 4
        for (int k = ks * 128; k < ks * 128 + 128; k++) {
            float wg = gw[(size_t)k * D_ + d];
            float wb = bw[(size_t)k * D_ + d];
            float c0 = cs[k], c1 = cs[C_ + k];
            g0 = fmaf(c0, wg, g0);
            g1 = fmaf(c1, wg, g1);
            bt0 = fmaf(c0, wb, bt0);
            bt1 = fmaf(c1, wb, bt1);
        }
        red[(ks * 64 + dl) * 4 + 0] = g0; red[(ks * 64 + dl) * 4 + 1] = g1;
        red[(ks * 64 + dl) * 4 + 2] = bt0; red[(ks * 64 + dl) * 4 + 3] = bt1;
        __syncthreads();
        if (ks == 0) {
            float s0 = 0.f, s1 = 0.f, s2 = 0.f, s3 = 0.f;
#pragma unroll
            for (int q = 0; q < 4; q++) {
                s0 += red[(q * 64 + dl) * 4 + 0]; s1 += red[(q * 64 + dl) * 4 + 1];
                s2 += red[(q * 64 + dl) * 4 + 2]; s3 += red[(q * 64 + dl) * 4 + 3];
            }
            float gbv = gb[d], bbv = bb[d];
            gamma[d] = s0 + gbv;
            gamma[D_ + d] = s1 + gbv;
            beta[d] = s2 + bbv;
            beta[D_ + d] = s3 + bbv;
        }
    } else if (bid < 1640) {
        // ---- transpose fp32 [K][N] -> bf16 [N][K] ----
        const float* W; short* Wt; int K, N, bx, by;
        int r = bid - 8;
        if (r < 1024)      { W = W_in;  Wt = Wint;  K = 512;  N = 2048; bx = r % 64; by = r / 64; }
        else if (r < 1536) { r -= 1024; W = W_out; Wt = Woutt; K = 1024; N = 512; bx = r % 16; by = r / 16; }
        else if (r < 1600) { r -= 1536; W = W_x;   Wt = Wxt;   K = 1024; N = 64;  bx = r % 2;  by = r / 2; }
        else               { r -= 1600; W = W_dt;  Wt = Wdtt;  K = 32;   N = 1024; bx = r;     by = 0; }
        float (*t)[33] = (float(*)[33])smem;
        int n0 = bx * 32, k0 = by * 32;
        int c = tid & 31, rr0 = tid >> 5;
#pragma unroll
        for (int rr = rr0; rr < 32; rr += 8)
            t[rr][c] = W[(size_t)(k0 + rr) * N + n0 + c];
        __syncthreads();
#pragma unroll
        for (int rr = rr0; rr < 32; rr += 8)
            Wt[(size_t)(n0 + rr) * K + k0 + c] = f2bf(t[c][rr]);
    } else {
        // ---- ln_stats: token = bid - 1640 ----
        int t = bid - 1640;
        float2 v = *(const float2*)(x + (size_t)t * D_ + tid * 2);
        float s = v.x + v.y;
        float s2 = fmaf(v.x, v.x, v.y * v.y);
#pragma unroll
        for (int o = 32; o >= 1; o >>= 1) {
            s += __shfl_down(s, o);
            s2 += __shfl_down(s2, o);
        }
        int wid = tid >> 6;
        if ((tid & 63) == 0) { smem[wid] = s; smem[4 + wid] = s2; }
        __syncthreads();
        if (tid == 0) {
            float sum = smem[0] + smem[1] + smem[2] + smem[3];
            float sum2 = smem[4] + smem[5] + smem[6] + smem[7];
            float mu = sum * (1.f / (float)D_);
            float var = sum2 * (1.f / (float)D_) - mu * mu;
            stats[t] = make_float2(mu, rsqrtf(var + 1e-5f));
        }
    }
}

// ---------------- bf16 MFMA GEMM: C[M][N] = A[M][K] * Bt[N][K]^T ----------------
template <int BM, int BN, bool FILM, bool LNA>
__global__ __launch_bounds__(256) void gemm_bf16(
    const void* __restrict__ Av, const short* __restrict__ Bt, float* __restrict__ C,
    int M, int N, int K,
    const float2* __restrict__ stats, const float* __restrict__ lng, const float* __restrict__ lnb,
    const float* __restrict__ gamma, const float* __restrict__ beta) {
    constexpr int BK = 64;
    constexpr int LDT = BK + 8;          // 72 shorts = 144B pitch
    constexpr int WM = BM / 2, WN = BN / 2;
    constexpr int MR = WM / 32, NR = WN / 32;
    __shared__ __align__(16) short As[BM * LDT];
    __shared__ __align__(16) short Bs[BN * LDT];
    int tid = threadIdx.x;
    int lane = tid & 63, w = tid >> 6;
    int wr = w >> 1, wc = w & 1;
    int m0 = blockIdx.y * BM, n0 = blockIdx.x * BN;

    f32x16 acc[MR][NR];
#pragma unroll
    for (int i = 0; i < MR; i++)
#pragma unroll
        for (int j = 0; j < NR; j++)
#pragma unroll
            for (int r = 0; r < 16; r++) acc[i][j][r] = 0.f;

    int l31 = lane & 31, hk = (lane >> 5) * 8;

    for (int k0 = 0; k0 < K; k0 += BK) {
        __syncthreads();
        if constexpr (LNA) {
            const float* Af = (const float*)Av;
#pragma unroll
            for (int i = tid; i < BM * 8; i += 256) {
                int r = i >> 3, c = (i & 7) * 8;
                float2 st = stats[m0 + r];
                const float* src = Af + (size_t)(m0 + r) * K + k0 + c;
                float4 v0 = *(const float4*)src;
                float4 v1 = *(const float4*)(src + 4);
                float4 g0 = *(const float4*)(lng + k0 + c);
                float4 g1 = *(const float4*)(lng + k0 + c + 4);
                float4 b0 = *(const float4*)(lnb + k0 + c);
                float4 b1 = *(const float4*)(lnb + k0 + c + 4);
                short8 o;
                o[0] = f2bf((v0.x - st.x) * st.y * g0.x + b0.x);
                o[1] = f2bf((v0.y - st.x) * st.y * g0.y + b0.y);
                o[2] = f2bf((v0.z - st.x) * st.y * g0.z + b0.z);
                o[3] = f2bf((v0.w - st.x) * st.y * g0.w + b0.w);
                o[4] = f2bf((v1.x - st.x) * st.y * g1.x + b1.x);
                o[5] = f2bf((v1.y - st.x) * st.y * g1.y + b1.y);
                o[6] = f2bf((v1.z - st.x) * st.y * g1.z + b1.z);
                o[7] = f2bf((v1.w - st.x) * st.y * g1.w + b1.w);
                *(short8*)&As[r * LDT + c] = o;
            }
        } else {
            const short* Ab = (const short*)Av;
#pragma unroll
            for (int i = tid; i < BM * 8; i += 256) {
                int r = i >> 3, c = (i & 7) * 8;
                *(short8*)&As[r * LDT + c] = *(const short8*)&Ab[(size_t)(m0 + r) * K + k0 + c];
            }
        }
#pragma unroll
        for (int i = tid; i < BN * 8; i += 256) {
            int r = i >> 3, c = (i & 7) * 8;
            *(short8*)&Bs[r * LDT + c] = *(const short8*)&Bt[(size_t)(n0 + r) * K + k0 + c];
        }
        __syncthreads();
#pragma unroll
        for (int kk = 0; kk < 4; kk++) {
            short8 a[MR], b[NR];
#pragma unroll
            for (int i = 0; i < MR; i++)
                a[i] = *(const short8*)&As[(wr * WM + i * 32 + l31) * LDT + kk * 16 + hk];
#pragma unroll
            for (int j = 0; j < NR; j++)
                b[j] = *(const short8*)&Bs[(wc * WN + j * 32 + l31) * LDT + kk * 16 + hk];
#pragma unroll
            for (int i = 0; i < MR; i++)
#pragma unroll
                for (int j = 0; j < NR; j++)
                    acc[i][j] = __builtin_amdgcn_mfma_f32_32x32x16_bf16(a[i], b[j], acc[i][j], 0, 0, 0);
        }
    }
    int rbase = 4 * (lane >> 5);
    int bi = m0 >> 11;   // batch index
#pragma unroll
    for (int i = 0; i < MR; i++)
#pragma unroll
        for (int j = 0; j < NR; j++) {
            int col = n0 + wc * WN + j * 32 + l31;
            float gm = 1.f, bt = 0.f;
            if (FILM) {
                gm = gamma[bi * D_ + col];
                bt = beta[bi * D_ + col];
            }
#pragma unroll
            for (int r = 0; r < 16; r++) {
                int row = m0 + wr * WM + i * 32 + rbase + (r & 3) + 8 * (r >> 2);
                float v = acc[i][j][r];
                if (FILM) v = gm * v + bt;
                C[(size_t)row * N + col] = v;
            }
        }
}

// ================= mid: conv+SiLU -> xproj MFMA -> dt MFMA, 16 tokens/block =================
__global__ __launch_bounds__(256) void mid_kernel(
    const float* __restrict__ xz, const float* __restrict__ cw, const float* __restrict__ cb,
    const short* __restrict__ Wxt,   // [64][1024] bf16
    const short* __restrict__ Wdtt,  // [1024][32] bf16
    const float* __restrict__ bdt,
    float* __restrict__ uc, float* __restrict__ xdbl, float* __restrict__ delta) {
    constexpr int LDU = 1032;                        // bf16 pitch: 2064B = 2-way max aliasing
    __shared__ __align__(16) short u[19 * LDU];      // 39.2 KB halo+uc
    __shared__ __align__(16) float xd[16 * 68];      // 4.35 KB x_dbl staging
    int tid = threadIdx.x;
    int t0 = blockIdx.x * 16;
    int n0 = t0 & (N_ - 1);
    // stage u-halo rows (tokens t0-3..t0+15) as bf16
    for (int i = tid; i < 19 * 128; i += 256) {
        int r = i >> 7;
        int c8 = (i & 127) * 8;
        short8 v = {0, 0, 0, 0, 0, 0, 0, 0};
        if (n0 + r - 3 >= 0) {
            const float* src = xz + (size_t)(t0 + r - 3) * (2 * E_) + c8;
            float4 a = *(const float4*)src;
            float4 b = *(const float4*)(src + 4);
            v[0] = f2bf(a.x); v[1] = f2bf(a.y); v[2] = f2bf(a.z); v[3] = f2bf(a.w);
            v[4] = f2bf(b.x); v[5] = f2bf(b.y); v[6] = f2bf(b.z); v[7] = f2bf(b.w);
        }
        *(short8*)&u[r * LDU + c8] = v;
    }
    __syncthreads();
    // conv + silu: 4 e-columns per thread; write uc fp32 global + bf16 in place (rows 0..15)
#pragma unroll
    for (int q = 0; q < 4; q++) {
        int e = tid + q * 256;
        float4 w = *(const float4*)(cw + e * 4);
        float cbv = cb[e];
        float u0 = bf2f(u[0 * LDU + e]);
        float u1 = bf2f(u[1 * LDU + e]);
        float u2 = bf2f(u[2 * LDU + e]);
#pragma unroll
        for (int n = 0; n < 16; n++) {
            float u3 = bf2f(u[(n + 3) * LDU + e]);
            float a = fmaf(w.x, u0, fmaf(w.y, u1, fmaf(w.z, u2, fmaf(w.w, u3, cbv))));
            float sig = 1.f / (1.f + __expf(-a));
            float v = a * sig;
            uc[(size_t)(t0 + n) * E_ + e] = v;
            u[n * LDU + e] = f2bf(v);
            u0 = u1; u1 = u2; u2 = u3;
        }
    }
    __syncthreads();
    // xproj: wave w -> x_dbl cols [w*16, w*16+16); A from LDS, B streamed from global (L2)
    int lane = tid & 63, w = tid >> 6;
    int l15 = lane & 15, kq = (lane >> 4) * 8;
    f32x4 acc = {0.f, 0.f, 0.f, 0.f};
#pragma unroll 8
    for (int k0 = 0; k0 < 32; k0++) {
        short8 af = *(const short8*)&u[l15 * LDU + k0 * 32 + kq];
        short8 bfr = *(const short8*)&Wxt[(size_t)(w * 16 + l15) * E_ + k0 * 32 + kq];
        acc = __builtin_amdgcn_mfma_f32_16x16x32_bf16(af, bfr, acc, 0, 0, 0);
    }
#pragma unroll
    for (int j = 0; j < 4; j++)
        xd[((lane >> 4) * 4 + j) * 68 + w * 16 + l15] = acc[j];
    __syncthreads();
    // write x_dbl to global (scan reads B,C from it)
    {
        int r = tid >> 4, c4 = (tid & 15) * 4;
        *(float4*)&xdbl[(size_t)(t0 + r) * 64 + c4] = *(const float4*)&xd[r * 68 + c4];
    }
    // dt: one 16x16x32 MFMA per 16-col e-tile; wave w handles e in [w*256, w*256+256)
    float av[8];
    *(float4*)&av[0] = *(const float4*)&xd[l15 * 68 + kq];
    *(float4*)&av[4] = *(const float4*)&xd[l15 * 68 + kq + 4];
    short8 ab;
#pragma unroll
    for (int j = 0; j < 8; j++) ab[j] = f2bf(av[j]);
    int row4 = (lane >> 4) * 4;
#pragma unroll 4
    for (int t = 0; t < 16; t++) {
        int e = w * 256 + t * 16 + l15;
        short8 bb = *(const short8*)&Wdtt[(size_t)e * 32 + kq];
        f32x4 c = {0.f, 0.f, 0.f, 0.f};
        c = __builtin_amdgcn_mfma_f32_16x16x32_bf16(ab, bb, c, 0, 0, 0);
        float bv = bdt[e];
#pragma unroll
        for (int j = 0; j < 4; j++) {
            float xv = c[j] + bv;
            float sp = (xv > 20.f) ? xv : log1pf(__expf(xv));
            delta[(size_t)(t0 + row4 + j) * E_ + e] = sp;
        }
    }
}

// ---------------- chunked selective scan, s-in-registers ----------------
__global__ __launch_bounds__(256) void scan_p1(const float* __restrict__ delta,
                                               const float* __restrict__ uc,
                                               const float* __restrict__ xdbl,
                                               const float* __restrict__ A_log,
                                               float* __restrict__ hend,
                                               float* __restrict__ cumd) {
    int blk = blockIdx.x;            // b*(NC_*4) + c*4 + eq
    int eq = blk & 3;
    int c = (blk >> 2) & (NC_ - 1);
    int b = blk >> 8;
    int tid = threadIdx.x;
    int e = eq * 256 + tid;
    __shared__ float Bsl[CH_][16];
    int base = (b * N_ + c * CH_) * 64;
    for (int i = tid; i < CH_ * 16; i += 256) {
        int n = i >> 4, col = i & 15;
        Bsl[n][col] = xdbl[base + n * 64 + R_ + col];
    }
    float Aes[16];
    const float4* al = (const float4*)(A_log + e * 16);
#pragma unroll
    for (int j = 0; j < 4; j++) {
        float4 a = al[j];
        Aes[j * 4 + 0] = -__expf(a.x);
        Aes[j * 4 + 1] = -__expf(a.y);
        Aes[j * 4 + 2] = -__expf(a.z);
        Aes[j * 4 + 3] = -__expf(a.w);
    }
    __syncthreads();
    float h[16];
#pragma unroll
    for (int s = 0; s < 16; s++) h[s] = 0.f;
    float cum = 0.f;
    const float* dp = delta + (size_t)(b * N_ + c * CH_) * E_ + e;
    const float* up = uc + (size_t)(b * N_ + c * CH_) * E_ + e;
#pragma unroll 2
    for (int n = 0; n < CH_; n++) {
        float dv = dp[n * E_];
        float uv = up[n * E_];
        float du = dv * uv;
        cum += dv;
        float Bl[16];
#pragma unroll
        for (int j = 0; j < 4; j++) *(float4*)&Bl[j * 4] = *(const float4*)&Bsl[n][j * 4];
#pragma unroll
        for (int s = 0; s < 16; s++) {
            float dA = __expf(dv * Aes[s]);
            h[s] = fmaf(dA, h[s], du * Bl[s]);
        }
    }
    size_t ob = (size_t)(b * NC_ + c) * 16 * E_ + e;
#pragma unroll
    for (int s = 0; s < 16; s++) hend[ob + (size_t)s * E_] = h[s];
    cumd[(size_t)(b * NC_ + c) * E_ + e] = cum;
}

__global__ __launch_bounds__(256) void scan_comb(float* __restrict__ hend,
                                                 const float* __restrict__ cumd,
                                                 const float* __restrict__ A_log) {
    int idx = blockIdx.x * 256 + threadIdx.x;   // over B*S*E = 32768
    int b = idx >> 14;
    int s = (idx >> 10) & 15;
    int e = idx & 1023;
    float Aes = -__expf(A_log[e * 16 + s]);
    float h = 0.f;
#pragma unroll 4
    for (int c = 0; c < NC_; c++) {
        size_t i = ((size_t)((b * NC_ + c) * 16) + s) * E_ + e;
        float he = hend[i];
        float P = __expf(Aes * cumd[(size_t)(b * NC_ + c) * E_ + e]);
        hend[i] = h;
        h = fmaf(P, h, he);
    }
}

__global__ __launch_bounds__(256) void scan_p3(const float* __restrict__ delta,
                                               const float* __restrict__ uc,
                                               const float* __restrict__ xdbl,
                                               const float* __restrict__ xz,
                                               const float* __restrict__ A_log,
                                               const float* __restrict__ D_skip,
                                               const float* __restrict__ hend,
                                               short* __restrict__ yb) {
    int blk = blockIdx.x;
    int eq = blk & 3;
    int c = (blk >> 2) & (NC_ - 1);
    int b = blk >> 8;
    int tid = threadIdx.x;
    int e = eq * 256 + tid;
    __shared__ float Bsl[CH_][16];
    __shared__ float Csl[CH_][16];
    int base = (b * N_ + c * CH_) * 64;
    for (int i = tid; i < CH_ * 32; i += 256) {
        int n = i >> 5, col = i & 31;
        float v = xdbl[base + n * 64 + R_ + col];
        if (col < 16) Bsl[n][col] = v;
        else Csl[n][col - 16] = v;
    }
    float Aes[16];
    const float4* al = (const float4*)(A_log + e * 16);
#pragma unroll
    for (int j = 0; j < 4; j++) {
        float4 a = al[j];
        Aes[j * 4 + 0] = -__expf(a.x);
        Aes[j * 4 + 1] = -__expf(a.y);
        Aes[j * 4 + 2] = -__expf(a.z);
        Aes[j * 4 + 3] = -__expf(a.w);
    }
    float dsk = D_skip[e];
    float h[16];
    size_t ob = (size_t)(b * NC_ + c) * 16 * E_ + e;
#pragma unroll
    for (int s = 0; s < 16; s++) h[s] = hend[ob + (size_t)s * E_];
    __syncthreads();
    const float* dp = delta + (size_t)(b * N_ + c * CH_) * E_ + e;
    const float* up = uc + (size_t)(b * N_ + c * CH_) * E_ + e;
    const float* zp = xz + (size_t)(b * N_ + c * CH_) * (2 * E_) + E_ + e;
    short* yp = yb + (size_t)(b * N_ + c * CH_) * E_ + e;
#pragma unroll 2
    for (int n = 0; n < CH_; n++) {
        float dv = dp[n * E_];
        float uv = up[n * E_];
        float du = dv * uv;
        float Bl[16], Cl[16];
#pragma unroll
        for (int j = 0; j < 4; j++) {
            *(float4*)&Bl[j * 4] = *(const float4*)&Bsl[n][j * 4];
            *(float4*)&Cl[j * 4] = *(const float4*)&Csl[n][j * 4];
        }
        float y = 0.f;
#pragma unroll
        for (int s = 0; s < 16; s++) {
            float dA = __expf(dv * Aes[s]);
            h[s] = fmaf(dA, h[s], du * Bl[s]);
            y = fmaf(h[s], Cl[s], y);
        }
        float zv = zp[n * 2 * E_];
        float yy = y + dsk * uv;
        yy = yy * (zv / (1.f + __expf(-zv)));
        yp[n * E_] = f2bf(yy);
    }
}

extern "C" void kernel_launch(void* const* d_in, const int* in_sizes, int n_in,
                              void* d_out, int out_size, void* d_ws, size_t ws_size,
                              hipStream_t stream) {
    const float* x       = (const float*)d_in[0];
    const float* cond    = (const float*)d_in[1];
    const float* ln_g    = (const float*)d_in[2];
    const float* ln_b    = (const float*)d_in[3];
    const float* W_in    = (const float*)d_in[4];
    const float* conv_w  = (const float*)d_in[5];
    const float* conv_b  = (const float*)d_in[6];
    const float* W_x     = (const float*)d_in[7];
    const float* W_dt    = (const float*)d_in[8];
    const float* b_dt    = (const float*)d_in[9];
    const float* A_log   = (const float*)d_in[10];
    const float* D_skip  = (const float*)d_in[11];
    const float* W_out   = (const float*)d_in[12];
    const float* film_gw = (const float*)d_in[13];
    const float* film_gb = (const float*)d_in[14];
    const float* film_bw = (const float*)d_in[15];
    const float* film_bb = (const float*)d_in[16];
    float* out = (float*)d_out;

    float* ws = (float*)d_ws;
    float* xz    = ws;                       // 8,388,608 f
    float* ucb   = xz + 8388608;             // 4,194,304 f
    float* xdbl  = ucb + 4194304;            //   262,144 f
    float* delta = xdbl + 262144;            // 4,194,304 f
    float* gamma = delta + 4194304;          //     1,024 f
    float* beta  = gamma + 1024;             //     1,024 f
    float2* stats = (float2*)(beta + 1024);  //     4,096 f2
    float* hend  = (float*)(stats + 4096);   // 2,097,152 f  (B*NC*S*E)
    float* cumd  = hend + 2097152;           //   131,072 f  (B*NC*E)
    short* Wint  = (short*)(cumd + 131072);  // 1,048,576 sh
    short* Woutt = Wint + 1048576;           //   524,288 sh
    short* yb    = Woutt + 524288;           // 4,194,304 sh
    short* Wxt   = yb + 4194304;             //    65,536 sh (W_x^T bf16 [64][1024])
    short* Wdtt  = Wxt + 65536;              //    32,768 sh (W_dt^T bf16 [1024][32])

    // prep: film2 + 4 weight transposes + ln_stats, one launch (5736 blocks)
    prep_kernel<<<5736, 256, 0, stream>>>(
        x, stats, W_in, Wint, W_out, Woutt, W_x, Wxt, W_dt, Wdtt,
        cond, film_gw, film_gb, film_bw, film_bb, gamma, beta);

    // xz = LN(x) @ W_in   [4096,512]x[512,2048], LN fused into A staging
    gemm_bf16<128, 128, false, true>
        <<<dim3(2 * E_ / 128, B_ * N_ / 128), 256, 0, stream>>>(
            x, Wint, xz, B_ * N_, 2 * E_, D_, stats, ln_g, ln_b, nullptr, nullptr);

    // conv+silu -> xproj -> dt, fused; 256 blocks of 16 tokens
    mid_kernel<<<B_ * N_ / 16, 256, 0, stream>>>(
        xz, conv_w, conv_b, Wxt, Wdtt, b_dt, ucb, xdbl, delta);

    scan_p1<<<B_ * NC_ * 4, 256, 0, stream>>>(delta, ucb, xdbl, A_log, hend, cumd);
    scan_comb<<<(B_ * S_ * E_) / 256, 256, 0, stream>>>(hend, cumd, A_log);
    scan_p3<<<B_ * NC_ * 4, 256, 0, stream>>>(delta, ucb, xdbl, xz, A_log, D_skip, hend, yb);

    // out = FiLM(y @ W_out)   [4096,1024]x[1024,512]
    gemm_bf16<128, 64, true, false>
        <<<dim3(D_ / 64, B_ * N_ / 128), 256, 0, stream>>>(
            yb, Woutt, out, B_ * N_, D_, E_, nullptr, nullptr, nullptr, gamma, beta);
}

// Round 7
// 169.563 us; speedup vs baseline: 11.5037x; 1.0546x over previous
//
#include <hip/hip_runtime.h>
#include <hip/hip_bf16.h>
#include <math.h>

#define B_ 2
#define N_ 2048
#define D_ 512
#define E_ 1024
#define S_ 16
#define KC_ 4
#define R_ 32
#define C_ 512
#define CH_ 32
#define NC_ (N_ / CH_)   // 64 chunks

using short8 = __attribute__((ext_vector_type(8))) short;
using f32x4  = __attribute__((ext_vector_type(4))) float;
using f32x16 = __attribute__((ext_vector_type(16))) float;

__device__ __forceinline__ short f2bf(float f) {
    union { float f; unsigned u; } x; x.f = f;
    unsigned r = (x.u + 0x7fffu + ((x.u >> 16) & 1u)) >> 16;
    return (short)r;
}
__device__ __forceinline__ float bf2f(short s) {
    union { unsigned u; float f; } x;
    x.u = ((unsigned)(unsigned short)s) << 16;
    return x.f;
}

// ================= prep: film2 | 4 transposes | ln_stats, one launch =================
// block ranges: [0,8) film2; [8,1032) W_in^T; [1032,1544) W_out^T;
//               [1544,1608) W_x^T; [1608,1640) W_dt^T; [1640,5736) ln_stats
__global__ __launch_bounds__(256) void prep_kernel(
    const float* __restrict__ x, float2* __restrict__ stats,
    const float* __restrict__ W_in, short* __restrict__ Wint,
    const float* __restrict__ W_out, short* __restrict__ Woutt,
    const float* __restrict__ W_x, short* __restrict__ Wxt,
    const float* __restrict__ W_dt, short* __restrict__ Wdtt,
    const float* __restrict__ cond,
    const float* __restrict__ gw, const float* __restrict__ gb,
    const float* __restrict__ bw, const float* __restrict__ bb,
    float* __restrict__ gamma, float* __restrict__ beta) {
    __shared__ __align__(16) float smem[2112];   // 8448 B, reused per job
    int bid = blockIdx.x;
    int tid = threadIdx.x;
    if (bid < 8) {
        // ---- film2: d0 = bid*64 ----
        float* cs = smem;            // [2][512]
        float* red = smem + 1024;    // [4][64][4]
        int d0 = bid * 64;
#pragma unroll
        for (int i = tid; i < 2 * C_ / 4; i += 256) {
            int b = i >> 7;
            int c4 = (i & 127) * 4;
            *(float4*)&cs[b * C_ + c4] = *(const float4*)(cond + (size_t)b * C_ + c4);
        }
        __syncthreads();
        int dl = tid & 63, ks = tid >> 6;
        int d = d0 + dl;
        float g0 = 0.f, g1 = 0.f, bt0 = 0.f, bt1 = 0.f;
#pragma unroll 4
        for (int k = ks * 128; k < ks * 128 + 128; k++) {
            float wg = gw[(size_t)k * D_ + d];
            float wb = bw[(size_t)k * D_ + d];
            float c0 = cs[k], c1 = cs[C_ + k];
            g0 = fmaf(c0, wg, g0);
            g1 = fmaf(c1, wg, g1);
            bt0 = fmaf(c0, wb, bt0);
            bt1 = fmaf(c1, wb, bt1);
        }
        red[(ks * 64 + dl) * 4 + 0] = g0; red[(ks * 64 + dl) * 4 + 1] = g1;
        red[(ks * 64 + dl) * 4 + 2] = bt0; red[(ks * 64 + dl) * 4 + 3] = bt1;
        __syncthreads();
        if (ks == 0) {
            float s0 = 0.f, s1 = 0.f, s2 = 0.f, s3 = 0.f;
#pragma unroll
            for (int q = 0; q < 4; q++) {
                s0 += red[(q * 64 + dl) * 4 + 0]; s1 += red[(q * 64 + dl) * 4 + 1];
                s2 += red[(q * 64 + dl) * 4 + 2]; s3 += red[(q * 64 + dl) * 4 + 3];
            }
            float gbv = gb[d], bbv = bb[d];
            gamma[d] = s0 + gbv;
            gamma[D_ + d] = s1 + gbv;
            beta[d] = s2 + bbv;
            beta[D_ + d] = s3 + bbv;
        }
    } else if (bid < 1640) {
        // ---- transpose fp32 [K][N] -> bf16 [N][K] ----
        const float* W; short* Wt; int K, N, bx, by;
        int r = bid - 8;
        if (r < 1024)      { W = W_in;  Wt = Wint;  K = 512;  N = 2048; bx = r % 64; by = r / 64; }
        else if (r < 1536) { r -= 1024; W = W_out; Wt = Woutt; K = 1024; N = 512; bx = r % 16; by = r / 16; }
        else if (r < 1600) { r -= 1536; W = W_x;   Wt = Wxt;   K = 1024; N = 64;  bx = r % 2;  by = r / 2; }
        else               { r -= 1600; W = W_dt;  Wt = Wdtt;  K = 32;   N = 1024; bx = r;     by = 0; }
        float (*t)[33] = (float(*)[33])smem;
        int n0 = bx * 32, k0 = by * 32;
        int c = tid & 31, rr0 = tid >> 5;
#pragma unroll
        for (int rr = rr0; rr < 32; rr += 8)
            t[rr][c] = W[(size_t)(k0 + rr) * N + n0 + c];
        __syncthreads();
#pragma unroll
        for (int rr = rr0; rr < 32; rr += 8)
            Wt[(size_t)(n0 + rr) * K + k0 + c] = f2bf(t[c][rr]);
    } else {
        // ---- ln_stats: token = bid - 1640 ----
        int t = bid - 1640;
        float2 v = *(const float2*)(x + (size_t)t * D_ + tid * 2);
        float s = v.x + v.y;
        float s2 = fmaf(v.x, v.x, v.y * v.y);
#pragma unroll
        for (int o = 32; o >= 1; o >>= 1) {
            s += __shfl_down(s, o);
            s2 += __shfl_down(s2, o);
        }
        int wid = tid >> 6;
        if ((tid & 63) == 0) { smem[wid] = s; smem[4 + wid] = s2; }
        __syncthreads();
        if (tid == 0) {
            float sum = smem[0] + smem[1] + smem[2] + smem[3];
            float sum2 = smem[4] + smem[5] + smem[6] + smem[7];
            float mu = sum * (1.f / (float)D_);
            float var = sum2 * (1.f / (float)D_) - mu * mu;
            stats[t] = make_float2(mu, rsqrtf(var + 1e-5f));
        }
    }
}

// ---------------- bf16 MFMA GEMM: C[M][N] = A[M][K] * Bt[N][K]^T ----------------
template <int BM, int BN, bool FILM, bool LNA>
__global__ __launch_bounds__(256) void gemm_bf16(
    const void* __restrict__ Av, const short* __restrict__ Bt, float* __restrict__ C,
    int M, int N, int K,
    const float2* __restrict__ stats, const float* __restrict__ lng, const float* __restrict__ lnb,
    const float* __restrict__ gamma, const float* __restrict__ beta) {
    constexpr int BK = 64;
    constexpr int LDT = BK + 8;          // 72 shorts = 144B pitch
    constexpr int WM = BM / 2, WN = BN / 2;
    constexpr int MR = WM / 32, NR = WN / 32;
    __shared__ __align__(16) short As[BM * LDT];
    __shared__ __align__(16) short Bs[BN * LDT];
    int tid = threadIdx.x;
    int lane = tid & 63, w = tid >> 6;
    int wr = w >> 1, wc = w & 1;
    int m0 = blockIdx.y * BM, n0 = blockIdx.x * BN;

    f32x16 acc[MR][NR];
#pragma unroll
    for (int i = 0; i < MR; i++)
#pragma unroll
        for (int j = 0; j < NR; j++)
#pragma unroll
            for (int r = 0; r < 16; r++) acc[i][j][r] = 0.f;

    int l31 = lane & 31, hk = (lane >> 5) * 8;

    for (int k0 = 0; k0 < K; k0 += BK) {
        __syncthreads();
        if constexpr (LNA) {
            const float* Af = (const float*)Av;
#pragma unroll
            for (int i = tid; i < BM * 8; i += 256) {
                int r = i >> 3, c = (i & 7) * 8;
                float2 st = stats[m0 + r];
                const float* src = Af + (size_t)(m0 + r) * K + k0 + c;
                float4 v0 = *(const float4*)src;
                float4 v1 = *(const float4*)(src + 4);
                float4 g0 = *(const float4*)(lng + k0 + c);
                float4 g1 = *(const float4*)(lng + k0 + c + 4);
                float4 b0 = *(const float4*)(lnb + k0 + c);
                float4 b1 = *(const float4*)(lnb + k0 + c + 4);
                short8 o;
                o[0] = f2bf((v0.x - st.x) * st.y * g0.x + b0.x);
                o[1] = f2bf((v0.y - st.x) * st.y * g0.y + b0.y);
                o[2] = f2bf((v0.z - st.x) * st.y * g0.z + b0.z);
                o[3] = f2bf((v0.w - st.x) * st.y * g0.w + b0.w);
                o[4] = f2bf((v1.x - st.x) * st.y * g1.x + b1.x);
                o[5] = f2bf((v1.y - st.x) * st.y * g1.y + b1.y);
                o[6] = f2bf((v1.z - st.x) * st.y * g1.z + b1.z);
                o[7] = f2bf((v1.w - st.x) * st.y * g1.w + b1.w);
                *(short8*)&As[r * LDT + c] = o;
            }
        } else {
            const short* Ab = (const short*)Av;
#pragma unroll
            for (int i = tid; i < BM * 8; i += 256) {
                int r = i >> 3, c = (i & 7) * 8;
                *(short8*)&As[r * LDT + c] = *(const short8*)&Ab[(size_t)(m0 + r) * K + k0 + c];
            }
        }
#pragma unroll
        for (int i = tid; i < BN * 8; i += 256) {
            int r = i >> 3, c = (i & 7) * 8;
            *(short8*)&Bs[r * LDT + c] = *(const short8*)&Bt[(size_t)(n0 + r) * K + k0 + c];
        }
        __syncthreads();
#pragma unroll
        for (int kk = 0; kk < 4; kk++) {
            short8 a[MR], b[NR];
#pragma unroll
            for (int i = 0; i < MR; i++)
                a[i] = *(const short8*)&As[(wr * WM + i * 32 + l31) * LDT + kk * 16 + hk];
#pragma unroll
            for (int j = 0; j < NR; j++)
                b[j] = *(const short8*)&Bs[(wc * WN + j * 32 + l31) * LDT + kk * 16 + hk];
#pragma unroll
            for (int i = 0; i < MR; i++)
#pragma unroll
                for (int j = 0; j < NR; j++)
                    acc[i][j] = __builtin_amdgcn_mfma_f32_32x32x16_bf16(a[i], b[j], acc[i][j], 0, 0, 0);
        }
    }
    int rbase = 4 * (lane >> 5);
    int bi = m0 >> 11;   // batch index
#pragma unroll
    for (int i = 0; i < MR; i++)
#pragma unroll
        for (int j = 0; j < NR; j++) {
            int col = n0 + wc * WN + j * 32 + l31;
            float gm = 1.f, bt = 0.f;
            if (FILM) {
                gm = gamma[bi * D_ + col];
                bt = beta[bi * D_ + col];
            }
#pragma unroll
            for (int r = 0; r < 16; r++) {
                int row = m0 + wr * WM + i * 32 + rbase + (r & 3) + 8 * (r >> 2);
                float v = acc[i][j][r];
                if (FILM) v = gm * v + bt;
                C[(size_t)row * N + col] = v;
            }
        }
}

// ================= mid: conv+SiLU -> xproj MFMA -> dt MFMA, 16 tokens/block, 8 waves =================
__global__ __launch_bounds__(512) void mid_kernel(
    const float* __restrict__ xz, const float* __restrict__ cw, const float* __restrict__ cb,
    const short* __restrict__ Wxt,   // [64][1024] bf16
    const short* __restrict__ Wdtt,  // [1024][32] bf16
    const float* __restrict__ bdt,
    float* __restrict__ uc, float* __restrict__ xdbl, float* __restrict__ delta) {
    constexpr int LDU = 1032;                        // bf16 pitch: 2064B = 2-way max aliasing
    __shared__ __align__(16) short u[19 * LDU];      // 39.2 KB halo+uc
    __shared__ __align__(16) float xd2[2][16 * 68];  // 8.7 KB x_dbl partial sums
    int tid = threadIdx.x;                           // 0..511 (8 waves)
    int t0 = blockIdx.x * 16;
    int n0 = t0 & (N_ - 1);
    // stage u-halo rows (tokens t0-3..t0+15) as bf16
    for (int i = tid; i < 19 * 128; i += 512) {
        int r = i >> 7;
        int c8 = (i & 127) * 8;
        short8 v = {0, 0, 0, 0, 0, 0, 0, 0};
        if (n0 + r - 3 >= 0) {
            const float* src = xz + (size_t)(t0 + r - 3) * (2 * E_) + c8;
            float4 a = *(const float4*)src;
            float4 b = *(const float4*)(src + 4);
            v[0] = f2bf(a.x); v[1] = f2bf(a.y); v[2] = f2bf(a.z); v[3] = f2bf(a.w);
            v[4] = f2bf(b.x); v[5] = f2bf(b.y); v[6] = f2bf(b.z); v[7] = f2bf(b.w);
        }
        *(short8*)&u[r * LDU + c8] = v;
    }
    __syncthreads();
    // conv + silu: 2 e-columns per thread; write uc fp32 global + bf16 in place (rows 0..15)
#pragma unroll
    for (int q = 0; q < 2; q++) {
        int e = tid + q * 512;
        float4 w = *(const float4*)(cw + e * 4);
        float cbv = cb[e];
        float u0 = bf2f(u[0 * LDU + e]);
        float u1 = bf2f(u[1 * LDU + e]);
        float u2 = bf2f(u[2 * LDU + e]);
#pragma unroll
        for (int n = 0; n < 16; n++) {
            float u3 = bf2f(u[(n + 3) * LDU + e]);
            float a = fmaf(w.x, u0, fmaf(w.y, u1, fmaf(w.z, u2, fmaf(w.w, u3, cbv))));
            float sig = 1.f / (1.f + __expf(-a));
            float v = a * sig;
            uc[(size_t)(t0 + n) * E_ + e] = v;
            u[n * LDU + e] = f2bf(v);
            u0 = u1; u1 = u2; u2 = u3;
        }
    }
    __syncthreads();
    // xproj: 8 waves; wave w -> cols [cg*16, cg*16+16), K-half kh; partials in xd2[kh]
    int lane = tid & 63, w = tid >> 6;
    int cg = w & 3, kh = w >> 2;
    int l15 = lane & 15, kq = (lane >> 4) * 8;
    f32x4 acc = {0.f, 0.f, 0.f, 0.f};
#pragma unroll 8
    for (int k0 = 0; k0 < 16; k0++) {
        int kk = kh * 512 + k0 * 32;
        short8 af = *(const short8*)&u[l15 * LDU + kk + kq];
        short8 bfr = *(const short8*)&Wxt[(size_t)(cg * 16 + l15) * E_ + kk + kq];
        acc = __builtin_amdgcn_mfma_f32_16x16x32_bf16(af, bfr, acc, 0, 0, 0);
    }
#pragma unroll
    for (int j = 0; j < 4; j++)
        xd2[kh][((lane >> 4) * 4 + j) * 68 + cg * 16 + l15] = acc[j];
    __syncthreads();
    // reduce K-halves, write x_dbl to global, keep sum in xd2[0]
    if (tid < 256) {
        int r = tid >> 4, c4 = (tid & 15) * 4;
        float4 a = *(const float4*)&xd2[0][r * 68 + c4];
        float4 b = *(const float4*)&xd2[1][r * 68 + c4];
        a.x += b.x; a.y += b.y; a.z += b.z; a.w += b.w;
        *(float4*)&xd2[0][r * 68 + c4] = a;
        *(float4*)&xdbl[(size_t)(t0 + r) * 64 + c4] = a;
    }
    __syncthreads();
    // dt: 8 waves x 8 e-tiles of 16; A-frag (dt cols 0..31) from xd2[0]
    float av[8];
    *(float4*)&av[0] = *(const float4*)&xd2[0][l15 * 68 + kq];
    *(float4*)&av[4] = *(const float4*)&xd2[0][l15 * 68 + kq + 4];
    short8 ab;
#pragma unroll
    for (int j = 0; j < 8; j++) ab[j] = f2bf(av[j]);
    int row4 = (lane >> 4) * 4;
#pragma unroll 4
    for (int t = 0; t < 8; t++) {
        int e = w * 128 + t * 16 + l15;
        short8 bb = *(const short8*)&Wdtt[(size_t)e * 32 + kq];
        f32x4 c = {0.f, 0.f, 0.f, 0.f};
        c = __builtin_amdgcn_mfma_f32_16x16x32_bf16(ab, bb, c, 0, 0, 0);
        float bv = bdt[e];
#pragma unroll
        for (int j = 0; j < 4; j++) {
            float xv = c[j] + bv;
            float sp = (xv > 20.f) ? xv : log1pf(__expf(xv));
            delta[(size_t)(t0 + row4 + j) * E_ + e] = sp;
        }
    }
}

// ---------------- chunked selective scan, s-in-registers ----------------
__global__ __launch_bounds__(256) void scan_p1(const float* __restrict__ delta,
                                               const float* __restrict__ uc,
                                               const float* __restrict__ xdbl,
                                               const float* __restrict__ A_log,
                                               float* __restrict__ hend,
                                               float* __restrict__ cumd) {
    int blk = blockIdx.x;            // b*(NC_*4) + c*4 + eq
    int eq = blk & 3;
    int c = (blk >> 2) & (NC_ - 1);
    int b = blk >> 8;
    int tid = threadIdx.x;
    int e = eq * 256 + tid;
    __shared__ float Bsl[CH_][16];
    int base = (b * N_ + c * CH_) * 64;
    for (int i = tid; i < CH_ * 16; i += 256) {
        int n = i >> 4, col = i & 15;
        Bsl[n][col] = xdbl[base + n * 64 + R_ + col];
    }
    float Aes[16];
    const float4* al = (const float4*)(A_log + e * 16);
#pragma unroll
    for (int j = 0; j < 4; j++) {
        float4 a = al[j];
        Aes[j * 4 + 0] = -__expf(a.x);
        Aes[j * 4 + 1] = -__expf(a.y);
        Aes[j * 4 + 2] = -__expf(a.z);
        Aes[j * 4 + 3] = -__expf(a.w);
    }
    __syncthreads();
    float h[16];
#pragma unroll
    for (int s = 0; s < 16; s++) h[s] = 0.f;
    float cum = 0.f;
    const float* dp = delta + (size_t)(b * N_ + c * CH_) * E_ + e;
    const float* up = uc + (size_t)(b * N_ + c * CH_) * E_ + e;
#pragma unroll 2
    for (int n = 0; n < CH_; n++) {
        float dv = dp[n * E_];
        float uv = up[n * E_];
        float du = dv * uv;
        cum += dv;
        float Bl[16];
#pragma unroll
        for (int j = 0; j < 4; j++) *(float4*)&Bl[j * 4] = *(const float4*)&Bsl[n][j * 4];
#pragma unroll
        for (int s = 0; s < 16; s++) {
            float dA = __expf(dv * Aes[s]);
            h[s] = fmaf(dA, h[s], du * Bl[s]);
        }
    }
    size_t ob = (size_t)(b * NC_ + c) * 16 * E_ + e;
#pragma unroll
    for (int s = 0; s < 16; s++) hend[ob + (size_t)s * E_] = h[s];
    cumd[(size_t)(b * NC_ + c) * E_ + e] = cum;
}

__global__ __launch_bounds__(256) void scan_comb(float* __restrict__ hend,
                                                 const float* __restrict__ cumd,
                                                 const float* __restrict__ A_log) {
    int idx = blockIdx.x * 256 + threadIdx.x;   // over B*S*E = 32768
    int b = idx >> 14;
    int s = (idx >> 10) & 15;
    int e = idx & 1023;
    float Aes = -__expf(A_log[e * 16 + s]);
    float h = 0.f;
#pragma unroll 4
    for (int c = 0; c < NC_; c++) {
        size_t i = ((size_t)((b * NC_ + c) * 16) + s) * E_ + e;
        float he = hend[i];
        float P = __expf(Aes * cumd[(size_t)(b * NC_ + c) * E_ + e]);
        hend[i] = h;
        h = fmaf(P, h, he);
    }
}

__global__ __launch_bounds__(256) void scan_p3(const float* __restrict__ delta,
                                               const float* __restrict__ uc,
                                               const float* __restrict__ xdbl,
                                               const float* __restrict__ xz,
                                               const float* __restrict__ A_log,
                                               const float* __restrict__ D_skip,
                                               const float* __restrict__ hend,
                                               short* __restrict__ yb) {
    int blk = blockIdx.x;
    int eq = blk & 3;
    int c = (blk >> 2) & (NC_ - 1);
    int b = blk >> 8;
    int tid = threadIdx.x;
    int e = eq * 256 + tid;
    __shared__ float Bsl[CH_][16];
    __shared__ float Csl[CH_][16];
    int base = (b * N_ + c * CH_) * 64;
    for (int i = tid; i < CH_ * 32; i += 256) {
        int n = i >> 5, col = i & 31;
        float v = xdbl[base + n * 64 + R_ + col];
        if (col < 16) Bsl[n][col] = v;
        else Csl[n][col - 16] = v;
    }
    float Aes[16];
    const float4* al = (const float4*)(A_log + e * 16);
#pragma unroll
    for (int j = 0; j < 4; j++) {
        float4 a = al[j];
        Aes[j * 4 + 0] = -__expf(a.x);
        Aes[j * 4 + 1] = -__expf(a.y);
        Aes[j * 4 + 2] = -__expf(a.z);
        Aes[j * 4 + 3] = -__expf(a.w);
    }
    float dsk = D_skip[e];
    float h[16];
    size_t ob = (size_t)(b * NC_ + c) * 16 * E_ + e;
#pragma unroll
    for (int s = 0; s < 16; s++) h[s] = hend[ob + (size_t)s * E_];
    __syncthreads();
    const float* dp = delta + (size_t)(b * N_ + c * CH_) * E_ + e;
    const float* up = uc + (size_t)(b * N_ + c * CH_) * E_ + e;
    const float* zp = xz + (size_t)(b * N_ + c * CH_) * (2 * E_) + E_ + e;
    short* yp = yb + (size_t)(b * N_ + c * CH_) * E_ + e;
#pragma unroll 2
    for (int n = 0; n < CH_; n++) {
        float dv = dp[n * E_];
        float uv = up[n * E_];
        float du = dv * uv;
        float Bl[16], Cl[16];
#pragma unroll
        for (int j = 0; j < 4; j++) {
            *(float4*)&Bl[j * 4] = *(const float4*)&Bsl[n][j * 4];
            *(float4*)&Cl[j * 4] = *(const float4*)&Csl[n][j * 4];
        }
        float y = 0.f;
#pragma unroll
        for (int s = 0; s < 16; s++) {
            float dA = __expf(dv * Aes[s]);
            h[s] = fmaf(dA, h[s], du * Bl[s]);
            y = fmaf(h[s], Cl[s], y);
        }
        float zv = zp[n * 2 * E_];
        float yy = y + dsk * uv;
        yy = yy * (zv / (1.f + __expf(-zv)));
        yp[n * E_] = f2bf(yy);
    }
}

extern "C" void kernel_launch(void* const* d_in, const int* in_sizes, int n_in,
                              void* d_out, int out_size, void* d_ws, size_t ws_size,
                              hipStream_t stream) {
    const float* x       = (const float*)d_in[0];
    const float* cond    = (const float*)d_in[1];
    const float* ln_g    = (const float*)d_in[2];
    const float* ln_b    = (const float*)d_in[3];
    const float* W_in    = (const float*)d_in[4];
    const float* conv_w  = (const float*)d_in[5];
    const float* conv_b  = (const float*)d_in[6];
    const float* W_x     = (const float*)d_in[7];
    const float* W_dt    = (const float*)d_in[8];
    const float* b_dt    = (const float*)d_in[9];
    const float* A_log   = (const float*)d_in[10];
    const float* D_skip  = (const float*)d_in[11];
    const float* W_out   = (const float*)d_in[12];
    const float* film_gw = (const float*)d_in[13];
    const float* film_gb = (const float*)d_in[14];
    const float* film_bw = (const float*)d_in[15];
    const float* film_bb = (const float*)d_in[16];
    float* out = (float*)d_out;

    float* ws = (float*)d_ws;
    float* xz    = ws;                       // 8,388,608 f
    float* ucb   = xz + 8388608;             // 4,194,304 f
    float* xdbl  = ucb + 4194304;            //   262,144 f
    float* delta = xdbl + 262144;            // 4,194,304 f
    float* gamma = delta + 4194304;          //     1,024 f
    float* beta  = gamma + 1024;             //     1,024 f
    float2* stats = (float2*)(beta + 1024);  //     4,096 f2
    float* hend  = (float*)(stats + 4096);   // 2,097,152 f  (B*NC*S*E)
    float* cumd  = hend + 2097152;           //   131,072 f  (B*NC*E)
    short* Wint  = (short*)(cumd + 131072);  // 1,048,576 sh
    short* Woutt = Wint + 1048576;           //   524,288 sh
    short* yb    = Woutt + 524288;           // 4,194,304 sh
    short* Wxt   = yb + 4194304;             //    65,536 sh (W_x^T bf16 [64][1024])
    short* Wdtt  = Wxt + 65536;              //    32,768 sh (W_dt^T bf16 [1024][32])

    // prep: film2 + 4 weight transposes + ln_stats, one launch (5736 blocks)
    prep_kernel<<<5736, 256, 0, stream>>>(
        x, stats, W_in, Wint, W_out, Woutt, W_x, Wxt, W_dt, Wdtt,
        cond, film_gw, film_gb, film_bw, film_bb, gamma, beta);

    // xz = LN(x) @ W_in   [4096,512]x[512,2048], LN fused into A staging
    gemm_bf16<128, 128, false, true>
        <<<dim3(2 * E_ / 128, B_ * N_ / 128), 256, 0, stream>>>(
            x, Wint, xz, B_ * N_, 2 * E_, D_, stats, ln_g, ln_b, nullptr, nullptr);

    // conv+silu -> xproj -> dt, fused; 256 blocks x 8 waves, 16 tokens each
    mid_kernel<<<B_ * N_ / 16, 512, 0, stream>>>(
        xz, conv_w, conv_b, Wxt, Wdtt, b_dt, ucb, xdbl, delta);

    scan_p1<<<B_ * NC_ * 4, 256, 0, stream>>>(delta, ucb, xdbl, A_log, hend, cumd);
    scan_comb<<<(B_ * S_ * E_) / 256, 256, 0, stream>>>(hend, cumd, A_log);
    scan_p3<<<B_ * NC_ * 4, 256, 0, stream>>>(delta, ucb, xdbl, xz, A_log, D_skip, hend, yb);

    // out = FiLM(y @ W_out)   [4096,1024]x[1024,512]
    gemm_bf16<128, 64, true, false>
        <<<dim3(D_ / 64, B_ * N_ / 128), 256, 0, stream>>>(
            yb, Woutt, out, B_ * N_, D_, E_, nullptr, nullptr, nullptr, gamma, beta);
}

// Round 8
// 162.206 us; speedup vs baseline: 12.0255x; 1.0454x over previous
//
#include <hip/hip_runtime.h>
#include <hip/hip_bf16.h>
#include <math.h>

#define B_ 2
#define N_ 2048
#define D_ 512
#define E_ 1024
#define S_ 16
#define KC_ 4
#define R_ 32
#define C_ 512
#define CH_ 32
#define NC_ (N_ / CH_)   // 64 chunks

using short8 = __attribute__((ext_vector_type(8))) short;
using f32x4  = __attribute__((ext_vector_type(4))) float;
using f32x16 = __attribute__((ext_vector_type(16))) float;

__device__ __forceinline__ short f2bf(float f) {
    union { float f; unsigned u; } x; x.f = f;
    unsigned r = (x.u + 0x7fffu + ((x.u >> 16) & 1u)) >> 16;
    return (short)r;
}
__device__ __forceinline__ float bf2f(short s) {
    union { unsigned u; float f; } x;
    x.u = ((unsigned)(unsigned short)s) << 16;
    return x.f;
}

// ================= prep: film2 | 4 transposes | ln_stats, one launch =================
__global__ __launch_bounds__(256) void prep_kernel(
    const float* __restrict__ x, float2* __restrict__ stats,
    const float* __restrict__ W_in, short* __restrict__ Wint,
    const float* __restrict__ W_out, short* __restrict__ Woutt,
    const float* __restrict__ W_x, short* __restrict__ Wxt,
    const float* __restrict__ W_dt, short* __restrict__ Wdtt,
    const float* __restrict__ cond,
    const float* __restrict__ gw, const float* __restrict__ gb,
    const float* __restrict__ bw, const float* __restrict__ bb,
    float* __restrict__ gamma, float* __restrict__ beta) {
    __shared__ __align__(16) float smem[2112];
    int bid = blockIdx.x;
    int tid = threadIdx.x;
    if (bid < 8) {
        float* cs = smem;            // [2][512]
        float* red = smem + 1024;    // [4][64][4]
        int d0 = bid * 64;
#pragma unroll
        for (int i = tid; i < 2 * C_ / 4; i += 256) {
            int b = i >> 7;
            int c4 = (i & 127) * 4;
            *(float4*)&cs[b * C_ + c4] = *(const float4*)(cond + (size_t)b * C_ + c4);
        }
        __syncthreads();
        int dl = tid & 63, ks = tid >> 6;
        int d = d0 + dl;
        float g0 = 0.f, g1 = 0.f, bt0 = 0.f, bt1 = 0.f;
#pragma unroll 4
        for (int k = ks * 128; k < ks * 128 + 128; k++) {
            float wg = gw[(size_t)k * D_ + d];
            float wb = bw[(size_t)k * D_ + d];
            float c0 = cs[k], c1 = cs[C_ + k];
            g0 = fmaf(c0, wg, g0);
            g1 = fmaf(c1, wg, g1);
            bt0 = fmaf(c0, wb, bt0);
            bt1 = fmaf(c1, wb, bt1);
        }
        red[(ks * 64 + dl) * 4 + 0] = g0; red[(ks * 64 + dl) * 4 + 1] = g1;
        red[(ks * 64 + dl) * 4 + 2] = bt0; red[(ks * 64 + dl) * 4 + 3] = bt1;
        __syncthreads();
        if (ks == 0) {
            float s0 = 0.f, s1 = 0.f, s2 = 0.f, s3 = 0.f;
#pragma unroll
            for (int q = 0; q < 4; q++) {
                s0 += red[(q * 64 + dl) * 4 + 0]; s1 += red[(q * 64 + dl) * 4 + 1];
                s2 += red[(q * 64 + dl) * 4 + 2]; s3 += red[(q * 64 + dl) * 4 + 3];
            }
            float gbv = gb[d], bbv = bb[d];
            gamma[d] = s0 + gbv;
            gamma[D_ + d] = s1 + gbv;
            beta[d] = s2 + bbv;
            beta[D_ + d] = s3 + bbv;
        }
    } else if (bid < 1640) {
        const float* W; short* Wt; int K, N, bx, by;
        int r = bid - 8;
        if (r < 1024)      { W = W_in;  Wt = Wint;  K = 512;  N = 2048; bx = r % 64; by = r / 64; }
        else if (r < 1536) { r -= 1024; W = W_out; Wt = Woutt; K = 1024; N = 512; bx = r % 16; by = r / 16; }
        else if (r < 1600) { r -= 1536; W = W_x;   Wt = Wxt;   K = 1024; N = 64;  bx = r % 2;  by = r / 2; }
        else               { r -= 1600; W = W_dt;  Wt = Wdtt;  K = 32;   N = 1024; bx = r;     by = 0; }
        float (*t)[33] = (float(*)[33])smem;
        int n0 = bx * 32, k0 = by * 32;
        int c = tid & 31, rr0 = tid >> 5;
#pragma unroll
        for (int rr = rr0; rr < 32; rr += 8)
            t[rr][c] = W[(size_t)(k0 + rr) * N + n0 + c];
        __syncthreads();
#pragma unroll
        for (int rr = rr0; rr < 32; rr += 8)
            Wt[(size_t)(n0 + rr) * K + k0 + c] = f2bf(t[c][rr]);
    } else {
        int t = bid - 1640;
        float2 v = *(const float2*)(x + (size_t)t * D_ + tid * 2);
        float s = v.x + v.y;
        float s2 = fmaf(v.x, v.x, v.y * v.y);
#pragma unroll
        for (int o = 32; o >= 1; o >>= 1) {
            s += __shfl_down(s, o);
            s2 += __shfl_down(s2, o);
        }
        int wid = tid >> 6;
        if ((tid & 63) == 0) { smem[wid] = s; smem[4 + wid] = s2; }
        __syncthreads();
        if (tid == 0) {
            float sum = smem[0] + smem[1] + smem[2] + smem[3];
            float sum2 = smem[4] + smem[5] + smem[6] + smem[7];
            float mu = sum * (1.f / (float)D_);
            float var = sum2 * (1.f / (float)D_) - mu * mu;
            stats[t] = make_float2(mu, rsqrtf(var + 1e-5f));
        }
    }
}

// ---------------- bf16 MFMA GEMM: C[M][N] = A[M][K] * Bt[N][K]^T ----------------
// LNA: A fp32 + LayerNorm in staging. FILM: gamma/beta epilogue. OBF: bf16 output.
template <int BM, int BN, bool FILM, bool LNA, bool OBF>
__global__ __launch_bounds__(256) void gemm_bf16(
    const void* __restrict__ Av, const short* __restrict__ Bt, void* __restrict__ Cv,
    int M, int N, int K,
    const float2* __restrict__ stats, const float* __restrict__ lng, const float* __restrict__ lnb,
    const float* __restrict__ gamma, const float* __restrict__ beta) {
    constexpr int BK = 64;
    constexpr int LDT = BK + 8;          // 72 shorts = 144B pitch
    constexpr int WM = BM / 2, WN = BN / 2;
    constexpr int MR = WM / 32, NR = WN / 32;
    __shared__ __align__(16) short As[BM * LDT];
    __shared__ __align__(16) short Bs[BN * LDT];
    int tid = threadIdx.x;
    int lane = tid & 63, w = tid >> 6;
    int wr = w >> 1, wc = w & 1;
    int m0 = blockIdx.y * BM, n0 = blockIdx.x * BN;

    f32x16 acc[MR][NR];
#pragma unroll
    for (int i = 0; i < MR; i++)
#pragma unroll
        for (int j = 0; j < NR; j++)
#pragma unroll
            for (int r = 0; r < 16; r++) acc[i][j][r] = 0.f;

    int l31 = lane & 31, hk = (lane >> 5) * 8;

    for (int k0 = 0; k0 < K; k0 += BK) {
        __syncthreads();
        if constexpr (LNA) {
            const float* Af = (const float*)Av;
#pragma unroll
            for (int i = tid; i < BM * 8; i += 256) {
                int r = i >> 3, c = (i & 7) * 8;
                float2 st = stats[m0 + r];
                const float* src = Af + (size_t)(m0 + r) * K + k0 + c;
                float4 v0 = *(const float4*)src;
                float4 v1 = *(const float4*)(src + 4);
                float4 g0 = *(const float4*)(lng + k0 + c);
                float4 g1 = *(const float4*)(lng + k0 + c + 4);
                float4 b0 = *(const float4*)(lnb + k0 + c);
                float4 b1 = *(const float4*)(lnb + k0 + c + 4);
                short8 o;
                o[0] = f2bf((v0.x - st.x) * st.y * g0.x + b0.x);
                o[1] = f2bf((v0.y - st.x) * st.y * g0.y + b0.y);
                o[2] = f2bf((v0.z - st.x) * st.y * g0.z + b0.z);
                o[3] = f2bf((v0.w - st.x) * st.y * g0.w + b0.w);
                o[4] = f2bf((v1.x - st.x) * st.y * g1.x + b1.x);
                o[5] = f2bf((v1.y - st.x) * st.y * g1.y + b1.y);
                o[6] = f2bf((v1.z - st.x) * st.y * g1.z + b1.z);
                o[7] = f2bf((v1.w - st.x) * st.y * g1.w + b1.w);
                *(short8*)&As[r * LDT + c] = o;
            }
        } else {
            const short* Ab = (const short*)Av;
#pragma unroll
            for (int i = tid; i < BM * 8; i += 256) {
                int r = i >> 3, c = (i & 7) * 8;
                *(short8*)&As[r * LDT + c] = *(const short8*)&Ab[(size_t)(m0 + r) * K + k0 + c];
            }
        }
#pragma unroll
        for (int i = tid; i < BN * 8; i += 256) {
            int r = i >> 3, c = (i & 7) * 8;
            *(short8*)&Bs[r * LDT + c] = *(const short8*)&Bt[(size_t)(n0 + r) * K + k0 + c];
        }
        __syncthreads();
#pragma unroll
        for (int kk = 0; kk < 4; kk++) {
            short8 a[MR], b[NR];
#pragma unroll
            for (int i = 0; i < MR; i++)
                a[i] = *(const short8*)&As[(wr * WM + i * 32 + l31) * LDT + kk * 16 + hk];
#pragma unroll
            for (int j = 0; j < NR; j++)
                b[j] = *(const short8*)&Bs[(wc * WN + j * 32 + l31) * LDT + kk * 16 + hk];
#pragma unroll
            for (int i = 0; i < MR; i++)
#pragma unroll
                for (int j = 0; j < NR; j++)
                    acc[i][j] = __builtin_amdgcn_mfma_f32_32x32x16_bf16(a[i], b[j], acc[i][j], 0, 0, 0);
        }
    }
    int rbase = 4 * (lane >> 5);
    int bi = m0 >> 11;   // batch index
#pragma unroll
    for (int i = 0; i < MR; i++)
#pragma unroll
        for (int j = 0; j < NR; j++) {
            int col = n0 + wc * WN + j * 32 + l31;
            float gm = 1.f, bt = 0.f;
            if (FILM) {
                gm = gamma[bi * D_ + col];
                bt = beta[bi * D_ + col];
            }
#pragma unroll
            for (int r = 0; r < 16; r++) {
                int row = m0 + wr * WM + i * 32 + rbase + (r & 3) + 8 * (r >> 2);
                float v = acc[i][j][r];
                if (FILM) v = gm * v + bt;
                if constexpr (OBF)
                    ((short*)Cv)[(size_t)row * N + col] = f2bf(v);
                else
                    ((float*)Cv)[(size_t)row * N + col] = v;
            }
        }
}

// ================= mid: conv+SiLU -> xproj MFMA -> dt MFMA, 16 tokens/block, 8 waves =================
__global__ __launch_bounds__(512) void mid_kernel(
    const short* __restrict__ xzb, const float* __restrict__ cw, const float* __restrict__ cb,
    const short* __restrict__ Wxt,   // [64][1024] bf16
    const short* __restrict__ Wdtt,  // [1024][32] bf16
    const float* __restrict__ bdt,
    short* __restrict__ ucb, float* __restrict__ xdbl, short* __restrict__ deltab) {
    constexpr int LDU = 1032;                        // bf16 pitch: 2064B = 2-way max aliasing
    __shared__ __align__(16) short u[19 * LDU];      // 39.2 KB halo+uc
    __shared__ __align__(16) float xd2[2][16 * 68];  // 8.7 KB x_dbl partial sums
    int tid = threadIdx.x;                           // 0..511 (8 waves)
    int t0 = blockIdx.x * 16;
    int n0 = t0 & (N_ - 1);
    // stage u-halo rows (tokens t0-3..t0+15), already bf16 in xzb
    for (int i = tid; i < 19 * 128; i += 512) {
        int r = i >> 7;
        int c8 = (i & 127) * 8;
        short8 v = {0, 0, 0, 0, 0, 0, 0, 0};
        if (n0 + r - 3 >= 0)
            v = *(const short8*)&xzb[(size_t)(t0 + r - 3) * (2 * E_) + c8];
        *(short8*)&u[r * LDU + c8] = v;
    }
    __syncthreads();
    // conv + silu: 2 e-columns per thread; write uc bf16 global + bf16 in place
#pragma unroll
    for (int q = 0; q < 2; q++) {
        int e = tid + q * 512;
        float4 w = *(const float4*)(cw + e * 4);
        float cbv = cb[e];
        float u0 = bf2f(u[0 * LDU + e]);
        float u1 = bf2f(u[1 * LDU + e]);
        float u2 = bf2f(u[2 * LDU + e]);
#pragma unroll
        for (int n = 0; n < 16; n++) {
            float u3 = bf2f(u[(n + 3) * LDU + e]);
            float a = fmaf(w.x, u0, fmaf(w.y, u1, fmaf(w.z, u2, fmaf(w.w, u3, cbv))));
            float sig = 1.f / (1.f + __expf(-a));
            float v = a * sig;
            short vb = f2bf(v);
            ucb[(size_t)(t0 + n) * E_ + e] = vb;
            u[n * LDU + e] = vb;
            u0 = u1; u1 = u2; u2 = u3;
        }
    }
    __syncthreads();
    // xproj: 8 waves; wave w -> cols [cg*16, cg*16+16), K-half kh; partials in xd2[kh]
    int lane = tid & 63, w = tid >> 6;
    int cg = w & 3, kh = w >> 2;
    int l15 = lane & 15, kq = (lane >> 4) * 8;
    f32x4 acc = {0.f, 0.f, 0.f, 0.f};
#pragma unroll 8
    for (int k0 = 0; k0 < 16; k0++) {
        int kk = kh * 512 + k0 * 32;
        short8 af = *(const short8*)&u[l15 * LDU + kk + kq];
        short8 bfr = *(const short8*)&Wxt[(size_t)(cg * 16 + l15) * E_ + kk + kq];
        acc = __builtin_amdgcn_mfma_f32_16x16x32_bf16(af, bfr, acc, 0, 0, 0);
    }
#pragma unroll
    for (int j = 0; j < 4; j++)
        xd2[kh][((lane >> 4) * 4 + j) * 68 + cg * 16 + l15] = acc[j];
    __syncthreads();
    // reduce K-halves, write x_dbl to global, keep sum in xd2[0]
    if (tid < 256) {
        int r = tid >> 4, c4 = (tid & 15) * 4;
        float4 a = *(const float4*)&xd2[0][r * 68 + c4];
        float4 b = *(const float4*)&xd2[1][r * 68 + c4];
        a.x += b.x; a.y += b.y; a.z += b.z; a.w += b.w;
        *(float4*)&xd2[0][r * 68 + c4] = a;
        *(float4*)&xdbl[(size_t)(t0 + r) * 64 + c4] = a;
    }
    __syncthreads();
    // dt: 8 waves x 8 e-tiles of 16; A-frag (dt cols 0..31) from xd2[0]
    float av[8];
    *(float4*)&av[0] = *(const float4*)&xd2[0][l15 * 68 + kq];
    *(float4*)&av[4] = *(const float4*)&xd2[0][l15 * 68 + kq + 4];
    short8 ab;
#pragma unroll
    for (int j = 0; j < 8; j++) ab[j] = f2bf(av[j]);
    int row4 = (lane >> 4) * 4;
#pragma unroll 4
    for (int t = 0; t < 8; t++) {
        int e = w * 128 + t * 16 + l15;
        short8 bb = *(const short8*)&Wdtt[(size_t)e * 32 + kq];
        f32x4 c = {0.f, 0.f, 0.f, 0.f};
        c = __builtin_amdgcn_mfma_f32_16x16x32_bf16(ab, bb, c, 0, 0, 0);
        float bv = bdt[e];
#pragma unroll
        for (int j = 0; j < 4; j++) {
            float xv = c[j] + bv;
            float sp = (xv > 20.f) ? xv : log1pf(__expf(xv));
            deltab[(size_t)(t0 + row4 + j) * E_ + e] = f2bf(sp);
        }
    }
}

// ---------------- chunked selective scan, s-in-registers (bf16 inputs) ----------------
__global__ __launch_bounds__(256) void scan_p1(const short* __restrict__ deltab,
                                               const short* __restrict__ ucb,
                                               const float* __restrict__ xdbl,
                                               const float* __restrict__ A_log,
                                               float* __restrict__ hend,
                                               float* __restrict__ cumd) {
    int blk = blockIdx.x;            // b*(NC_*4) + c*4 + eq
    int eq = blk & 3;
    int c = (blk >> 2) & (NC_ - 1);
    int b = blk >> 8;
    int tid = threadIdx.x;
    int e = eq * 256 + tid;
    __shared__ float Bsl[CH_][16];
    int base = (b * N_ + c * CH_) * 64;
    for (int i = tid; i < CH_ * 16; i += 256) {
        int n = i >> 4, col = i & 15;
        Bsl[n][col] = xdbl[base + n * 64 + R_ + col];
    }
    float Aes[16];
    const float4* al = (const float4*)(A_log + e * 16);
#pragma unroll
    for (int j = 0; j < 4; j++) {
        float4 a = al[j];
        Aes[j * 4 + 0] = -__expf(a.x);
        Aes[j * 4 + 1] = -__expf(a.y);
        Aes[j * 4 + 2] = -__expf(a.z);
        Aes[j * 4 + 3] = -__expf(a.w);
    }
    __syncthreads();
    float h[16];
#pragma unroll
    for (int s = 0; s < 16; s++) h[s] = 0.f;
    float cum = 0.f;
    const short* dp = deltab + (size_t)(b * N_ + c * CH_) * E_ + e;
    const short* up = ucb + (size_t)(b * N_ + c * CH_) * E_ + e;
#pragma unroll 2
    for (int n = 0; n < CH_; n++) {
        float dv = bf2f(dp[n * E_]);
        float uv = bf2f(up[n * E_]);
        float du = dv * uv;
        cum += dv;
        float Bl[16];
#pragma unroll
        for (int j = 0; j < 4; j++) *(float4*)&Bl[j * 4] = *(const float4*)&Bsl[n][j * 4];
#pragma unroll
        for (int s = 0; s < 16; s++) {
            float dA = __expf(dv * Aes[s]);
            h[s] = fmaf(dA, h[s], du * Bl[s]);
        }
    }
    size_t ob = (size_t)(b * NC_ + c) * 16 * E_ + e;
#pragma unroll
    for (int s = 0; s < 16; s++) hend[ob + (size_t)s * E_] = h[s];
    cumd[(size_t)(b * NC_ + c) * E_ + e] = cum;
}

__global__ __launch_bounds__(256) void scan_comb(float* __restrict__ hend,
                                                 const float* __restrict__ cumd,
                                                 const float* __restrict__ A_log) {
    int idx = blockIdx.x * 256 + threadIdx.x;   // over B*S*E = 32768
    int b = idx >> 14;
    int s = (idx >> 10) & 15;
    int e = idx & 1023;
    float Aes = -__expf(A_log[e * 16 + s]);
    float h = 0.f;
#pragma unroll 4
    for (int c = 0; c < NC_; c++) {
        size_t i = ((size_t)((b * NC_ + c) * 16) + s) * E_ + e;
        float he = hend[i];
        float P = __expf(Aes * cumd[(size_t)(b * NC_ + c) * E_ + e]);
        hend[i] = h;
        h = fmaf(P, h, he);
    }
}

__global__ __launch_bounds__(256) void scan_p3(const short* __restrict__ deltab,
                                               const short* __restrict__ ucb,
                                               const float* __restrict__ xdbl,
                                               const short* __restrict__ xzb,
                                               const float* __restrict__ A_log,
                                               const float* __restrict__ D_skip,
                                               const float* __restrict__ hend,
                                               short* __restrict__ yb) {
    int blk = blockIdx.x;
    int eq = blk & 3;
    int c = (blk >> 2) & (NC_ - 1);
    int b = blk >> 8;
    int tid = threadIdx.x;
    int e = eq * 256 + tid;
    __shared__ float Bsl[CH_][16];
    __shared__ float Csl[CH_][16];
    int base = (b * N_ + c * CH_) * 64;
    for (int i = tid; i < CH_ * 32; i += 256) {
        int n = i >> 5, col = i & 31;
        float v = xdbl[base + n * 64 + R_ + col];
        if (col < 16) Bsl[n][col] = v;
        else Csl[n][col - 16] = v;
    }
    float Aes[16];
    const float4* al = (const float4*)(A_log + e * 16);
#pragma unroll
    for (int j = 0; j < 4; j++) {
        float4 a = al[j];
        Aes[j * 4 + 0] = -__expf(a.x);
        Aes[j * 4 + 1] = -__expf(a.y);
        Aes[j * 4 + 2] = -__expf(a.z);
        Aes[j * 4 + 3] = -__expf(a.w);
    }
    float dsk = D_skip[e];
    float h[16];
    size_t ob = (size_t)(b * NC_ + c) * 16 * E_ + e;
#pragma unroll
    for (int s = 0; s < 16; s++) h[s] = hend[ob + (size_t)s * E_];
    __syncthreads();
    const short* dp = deltab + (size_t)(b * N_ + c * CH_) * E_ + e;
    const short* up = ucb + (size_t)(b * N_ + c * CH_) * E_ + e;
    const short* zp = xzb + (size_t)(b * N_ + c * CH_) * (2 * E_) + E_ + e;
    short* yp = yb + (size_t)(b * N_ + c * CH_) * E_ + e;
#pragma unroll 2
    for (int n = 0; n < CH_; n++) {
        float dv = bf2f(dp[n * E_]);
        float uv = bf2f(up[n * E_]);
        float du = dv * uv;
        float Bl[16], Cl[16];
#pragma unroll
        for (int j = 0; j < 4; j++) {
            *(float4*)&Bl[j * 4] = *(const float4*)&Bsl[n][j * 4];
            *(float4*)&Cl[j * 4] = *(const float4*)&Csl[n][j * 4];
        }
        float y = 0.f;
#pragma unroll
        for (int s = 0; s < 16; s++) {
            float dA = __expf(dv * Aes[s]);
            h[s] = fmaf(dA, h[s], du * Bl[s]);
            y = fmaf(h[s], Cl[s], y);
        }
        float zv = bf2f(zp[n * 2 * E_]);
        float yy = y + dsk * uv;
        yy = yy * (zv / (1.f + __expf(-zv)));
        yp[n * E_] = f2bf(yy);
    }
}

extern "C" void kernel_launch(void* const* d_in, const int* in_sizes, int n_in,
                              void* d_out, int out_size, void* d_ws, size_t ws_size,
                              hipStream_t stream) {
    const float* x       = (const float*)d_in[0];
    const float* cond    = (const float*)d_in[1];
    const float* ln_g    = (const float*)d_in[2];
    const float* ln_b    = (const float*)d_in[3];
    const float* W_in    = (const float*)d_in[4];
    const float* conv_w  = (const float*)d_in[5];
    const float* conv_b  = (const float*)d_in[6];
    const float* W_x     = (const float*)d_in[7];
    const float* W_dt    = (const float*)d_in[8];
    const float* b_dt    = (const float*)d_in[9];
    const float* A_log   = (const float*)d_in[10];
    const float* D_skip  = (const float*)d_in[11];
    const float* W_out   = (const float*)d_in[12];
    const float* film_gw = (const float*)d_in[13];
    const float* film_gb = (const float*)d_in[14];
    const float* film_bw = (const float*)d_in[15];
    const float* film_bb = (const float*)d_in[16];
    float* out = (float*)d_out;

    float* ws = (float*)d_ws;
    float* xdbl  = ws;                       //   262,144 f
    float* gamma = xdbl + 262144;            //     1,024 f
    float* beta  = gamma + 1024;             //     1,024 f
    float2* stats = (float2*)(beta + 1024);  //     4,096 f2
    float* hend  = (float*)(stats + 4096);   // 2,097,152 f  (B*NC*S*E)
    float* cumd  = hend + 2097152;           //   131,072 f  (B*NC*E)
    short* xzb   = (short*)(cumd + 131072);  // 8,388,608 sh (bf16 xz)
    short* ucb   = xzb + 8388608;            // 4,194,304 sh (bf16 uc)
    short* deltab = ucb + 4194304;           // 4,194,304 sh (bf16 delta)
    short* Wint  = deltab + 4194304;         // 1,048,576 sh
    short* Woutt = Wint + 1048576;           //   524,288 sh
    short* yb    = Woutt + 524288;           // 4,194,304 sh
    short* Wxt   = yb + 4194304;             //    65,536 sh
    short* Wdtt  = Wxt + 65536;              //    32,768 sh

    // prep: film2 + 4 weight transposes + ln_stats, one launch (5736 blocks)
    prep_kernel<<<5736, 256, 0, stream>>>(
        x, stats, W_in, Wint, W_out, Woutt, W_x, Wxt, W_dt, Wdtt,
        cond, film_gw, film_gb, film_bw, film_bb, gamma, beta);

    // xz = LN(x) @ W_in   [4096,512]x[512,2048], LN fused, bf16 output
    gemm_bf16<128, 128, false, true, true>
        <<<dim3(2 * E_ / 128, B_ * N_ / 128), 256, 0, stream>>>(
            x, Wint, xzb, B_ * N_, 2 * E_, D_, stats, ln_g, ln_b, nullptr, nullptr);

    // conv+silu -> xproj -> dt, fused; 256 blocks x 8 waves, 16 tokens each
    mid_kernel<<<B_ * N_ / 16, 512, 0, stream>>>(
        xzb, conv_w, conv_b, Wxt, Wdtt, b_dt, ucb, xdbl, deltab);

    scan_p1<<<B_ * NC_ * 4, 256, 0, stream>>>(deltab, ucb, xdbl, A_log, hend, cumd);
    scan_comb<<<(B_ * S_ * E_) / 256, 256, 0, stream>>>(hend, cumd, A_log);
    scan_p3<<<B_ * NC_ * 4, 256, 0, stream>>>(deltab, ucb, xdbl, xzb, A_log, D_skip, hend, yb);

    // out = FiLM(y @ W_out)   [4096,1024]x[1024,512], fp32 output
    gemm_bf16<128, 64, true, false, false>
        <<<dim3(D_ / 64, B_ * N_ / 128), 256, 0, stream>>>(
            yb, Woutt, out, B_ * N_, D_, E_, nullptr, nullptr, nullptr, gamma, beta);
}